// Round 11
// baseline (98.671 us; speedup 1.0000x reference)
//
#include <hip/hip_runtime.h>
#include <cstdint>
#include <cstddef>

#define HH 128
#define WW 128
#define LL 16384   // HH*WW
#define BL 32768   // B*LL

typedef float  f32x4  __attribute__((ext_vector_type(4)));
typedef __fp16 h2     __attribute__((ext_vector_type(2)));
typedef __fp16 h8     __attribute__((ext_vector_type(8)));

union U32H { unsigned u; h2 h; };

static __device__ __forceinline__ float fdot2(h2 a, h2 b, float c) {
  return __builtin_amdgcn_fdot2(a, b, c, false);
}
static __device__ __forceinline__ unsigned pkh2(float a, float b) {
  h2 h = __builtin_amdgcn_cvt_pkrtz(a, b);
  U32H t; t.h = h; return t.u;
}
static __device__ __forceinline__ h2 bcasth(float a) {
  return __builtin_amdgcn_cvt_pkrtz(a, a);
}
static __device__ __forceinline__ unsigned short f2h(float x) {
  union { __fp16 h; unsigned short u; } c; c.h = (__fp16)x; return c.u;
}

#define LOADH8(dst, ptr) { \
  uint4 _a = *(const uint4*)(ptr); uint4 _b = *(const uint4*)((ptr)+8); U32H _t; \
  _t.u=_a.x; dst[0]=_t.h; _t.u=_a.y; dst[1]=_t.h; _t.u=_a.z; dst[2]=_t.h; _t.u=_a.w; dst[3]=_t.h; \
  _t.u=_b.x; dst[4]=_t.h; _t.u=_b.y; dst[5]=_t.h; _t.u=_b.z; dst[6]=_t.h; _t.u=_b.w; dst[7]=_t.h; }

// ---- k0: fold proj into fusion weight (fp16 B^T [64][800], kk = t*32+c); cast w1/w2 --
__global__ __launch_bounds__(256) void k_combine(
    const float* __restrict__ proj_w, const float* __restrict__ proj_b,
    const float* __restrict__ fw, const float* __restrict__ fb,
    const float* __restrict__ w1, const float* __restrict__ w2,
    unsigned short* __restrict__ wctT, float* __restrict__ bc,
    unsigned short* __restrict__ w1h, unsigned short* __restrict__ w2h)
{
  if (blockIdx.x == 200) {
    int o = threadIdx.x;
    if (o < 64) {
      float acc = proj_b[o];
      for (int m = 0; m < 64; ++m) acc = fmaf(proj_w[o*64+m], fb[m], acc);
      bc[o] = acc;
    }
    return;
  }
  if (blockIdx.x == 201) {
    for (int i = threadIdx.x; i < 8192; i += 256) w1h[i] = f2h(w1[i]);
    return;
  }
  if (blockIdx.x == 202) {
    for (int i = threadIdx.x; i < 8192; i += 256) w2h[i] = f2h(w2[i]);
    return;
  }
  int gid = blockIdx.x * 256 + threadIdx.x;   // 0..51199 = o*800 + kk
  int o  = gid / 800;
  int kk = gid - o * 800;
  int c  = kk & 31;        // de-interleaved channel (nh*16+d)
  int t  = kk >> 5;        // window position 0..24
  int in = c * 25 + t;     // fusion weight flat index
  float acc = 0.f;
  for (int m = 0; m < 64; ++m) acc = fmaf(proj_w[o*64+m], fw[m*800+in], acc);
  wctT[gid] = f2h(acc);
}

// ---- k1: LayerNorm + QKV, fp16 out, de-interleaved (c' = nh*16 + d); 3-way split ----
__global__ __launch_bounds__(128) void k_ln_qkv(
    const float* __restrict__ x, const float* __restrict__ qkv_w,
    const float* __restrict__ qkv_b, const float* __restrict__ n1w,
    const float* __restrict__ n1b, unsigned short* __restrict__ qo,
    unsigned short* __restrict__ ko, unsigned short* __restrict__ vo)
{
  __shared__ float sW[32*32];
  __shared__ float sB[32];
  __shared__ float sNw[32], sNb[32];
  int p = blockIdx.y;                         // 0=q 1=k 2=v
  for (int i = threadIdx.x; i < 32*32; i += 128) sW[i] = qkv_w[p*1024 + i];
  if (threadIdx.x < 32) {
    sB[threadIdx.x]  = qkv_b[p*32 + threadIdx.x];
    sNw[threadIdx.x] = n1w[threadIdx.x];
    sNb[threadIdx.x] = n1b[threadIdx.x];
  }
  __syncthreads();
  int gid = blockIdx.x * 128 + threadIdx.x;   // 0..BL-1
  int b = gid >> 14, l = gid & (LL - 1);
  const float* xp = x + (size_t)b * 32 * LL + l;
  float xv[32];
  float mean = 0.f;
  #pragma unroll
  for (int c = 0; c < 32; ++c) { xv[c] = xp[(size_t)c * LL]; mean += xv[c]; }
  mean *= 0.03125f;
  float var = 0.f;
  #pragma unroll
  for (int c = 0; c < 32; ++c) { float d = xv[c] - mean; var = fmaf(d, d, var); }
  float rs = rsqrtf(var * 0.03125f + 1e-5f);
  #pragma unroll
  for (int c = 0; c < 32; ++c) xv[c] = (xv[c] - mean) * rs * sNw[c] + sNb[c];
  float ao[32];
  #pragma unroll
  for (int o = 0; o < 32; ++o) {
    const float* wr = &sW[o * 32];
    float acc = sB[o];
    #pragma unroll
    for (int c = 0; c < 32; ++c) acc = fmaf(xv[c], wr[c], acc);
    ao[(o & 1) * 16 + (o >> 1)] = acc;        // de-interleave heads
  }
  unsigned short* op = (p == 0 ? qo : p == 1 ? ko : vo) + (size_t)gid * 32;
  #pragma unroll
  for (int e = 0; e < 4; ++e) {
    uint4 pk4;
    pk4.x = pkh2(ao[e*8+0], ao[e*8+1]);
    pk4.y = pkh2(ao[e*8+2], ao[e*8+3]);
    pk4.z = pkh2(ao[e*8+4], ao[e*8+5]);
    pk4.w = pkh2(ao[e*8+6], ao[e*8+7]);
    *(uint4*)(op + e*8) = pk4;
  }
}

// ---- k2: tiled windowed attention (fused QK-exp-PV, tq-PAIR, fp16 PV) + MFMA f16 ----
// Block = 2x8 = 16 locations, 256 threads (4 waves). Quarter-wave task slots.
// 2 compute + 2 MFMA phases. 2048 blocks -> 8 blocks/CU of work, 4 resident.
#define TH 2
#define TW 8
#define NPOS 72   // 6x12 halo
#define KVSTR 26  // per-head fp16 row stride in ushorts (52B = 13 dwords, odd)
#define OSTRU 516 // sO row stride (ushorts): 512 kk + 4 pad

__global__ __launch_bounds__(256, 4) void k_attn(
    const unsigned short* __restrict__ qi, const unsigned short* __restrict__ ki,
    const unsigned short* __restrict__ vi, const float* __restrict__ rel_table,
    const unsigned short* __restrict__ wctT, const float* __restrict__ bc,
    float* __restrict__ y2)
{
  __shared__ __align__(16) unsigned short sQ[144*KVSTR]; // 7488 B ([nh*72+pos][16+pad])
  __shared__ __align__(16) unsigned short sK[144*KVSTR]; // 7488 B
  __shared__ __align__(16) unsigned short sV[144*KVSTR]; // 7488 B
  __shared__ __align__(16) unsigned short sO[16*OSTRU];  // 16512 B
  __shared__ float sRT[162];
  __shared__ float sPar[NPOS];
  // total ~39.9 KB -> 4 blocks/CU

  int tid = threadIdx.x;
  int lane = tid & 63, wv = tid >> 6;
  int b  = blockIdx.z;
  int h0 = blockIdx.y * TH, w0 = blockIdx.x * TW;

  for (int i = tid; i < 162; i += 256) sRT[i] = rel_table[i];
  if (tid < NPOS) {
    int ph = tid / 12, pw = tid - ph * 12;
    int h2v = h0 + ph - 2, w2v = w0 + pw - 2;
    bool valid = ((unsigned)h2v < HH) && ((unsigned)w2v < WW);
    sPar[tid] = (valid && (((h2v + w2v) & 1) == 1)) ? 1.f : 0.f;
  }
  // halo staging: 3 arrays x 72 pos x 2 nh x 2 half-chunks(16B) = 864 units
  for (int idx = tid; idx < 864; idx += 256) {
    int arr = idx / 288;                  // 0=K, 1=V, 2=Q
    int rem = idx - arr * 288;
    int pos = rem >> 2, q4 = rem & 3;
    int nh = q4 >> 1, half = q4 & 1;
    int ph = pos / 12, pw = pos - ph * 12;
    int h2v = h0 + ph - 2, w2v = w0 + pw - 2;
    uint4 val = make_uint4(0u, 0u, 0u, 0u);
    if (((unsigned)h2v < HH) && ((unsigned)w2v < WW)) {
      const unsigned short* src = (arr == 0 ? ki : arr == 1 ? vi : qi)
                       + ((size_t)((b << 14) + (h2v << 7) + w2v)) * 32 + nh * 16 + half * 8;
      val = *(const uint4*)src;
    }
    unsigned short* dp = (arr == 0 ? sK : arr == 1 ? sV : sQ)
                       + (nh * 72 + pos) * KVSTR + half * 8;
    *(uint4*)dp = val;
  }
  __syncthreads();

  f32x4 acc = {0.f, 0.f, 0.f, 0.f};
  int ocol = wv * 16 + (lane & 15);

  for (int it = 0; it < 2; ++it) {
    int slot = wv * 4 + (lane >> 4);          // 0..15, quarter-wave uniform
    int pr = slot >> 1;                       // pair 0..7
    int nh = slot & 1;
    int nhb = nh * 72;
    int tqb = it * 16;
    int tq0 = tqb + 2*pr;
    if (tq0 <= 24) {
      int nrr = (tq0 + 1 <= 24) ? 2 : 1;      // quarter-wave uniform
      int tq1 = tq0 + 1;
      int loc = lane & 15;
      int ly = loc >> 3, lx = loc & 7;
      int posb = ly * 12 + lx;
      int iq0 = tq0/5, jq0 = tq0 - iq0*5;
      int iq1 = tq1/5, jq1 = tq1 - iq1*5;
      int pq0 = posb + iq0*12 + jq0; pq0 = pq0 > 71 ? 71 : pq0;
      int pq1 = posb + iq1*12 + jq1; pq1 = pq1 > 71 ? 71 : pq1;
      float parq0 = sPar[pq0], parq1 = sPar[pq1];
      h2 q0[8], q1[8];
      LOADH8(q0, &sQ[(nhb+pq0)*KVSTR]);
      LOADH8(q1, &sQ[(nhb+pq1)*KVSTR]);
      float s0 = 0.f, s1 = 0.f;
      h2 oo0[8], oo1[8];
      #pragma unroll
      for (int e = 0; e < 8; ++e) { oo0[e] = (h2)(__fp16)0.f; oo1[e] = (h2)(__fp16)0.f; }
      #pragma unroll 1
      for (int ik = 0; ik < 5; ++ik) {
        int rb0 = ((iq0-ik+4)*9 + jq0 + 4)*2 + nh;
        int rb1 = ((iq1-ik+4)*9 + jq1 + 4)*2 + nh;
        #pragma unroll
        for (int jk = 0; jk < 5; ++jk) {
          int pk = posb + ik*12 + jk;
          h2 kh[8];
          LOADH8(kh, &sK[(nhb+pk)*KVSTR]);
          float park = sPar[pk];
          float mk = (park == 1.f) ? 0.f : -100.f;
          float a0 = 0.f, a1 = 0.f;
          #pragma unroll
          for (int u = 0; u < 8; ++u) {
            a0 = fdot2(q0[u], kh[u], a0);
            a1 = fdot2(q1[u], kh[u], a1);
          }
          int i0 = rb0 - 2*jk; i0 = i0 > 161 ? 161 : i0;
          int i1 = rb1 - 2*jk; i1 = i1 > 161 ? 161 : i1;
          float e0 = __expf(fmaf(parq0, mk, fmaf(a0, 0.25f, sRT[i0])));
          float e1 = __expf(fmaf(parq1, mk, fmaf(a1, 0.25f, sRT[i1])));
          s0 += e0; s1 += e1;
          h2 e0h = bcasth(e0), e1h = bcasth(e1);
          h2 vh[8];
          LOADH8(vh, &sV[(nhb+pk)*KVSTR]);
          #pragma unroll
          for (int u = 0; u < 8; ++u) {
            oo0[u] = e0h * vh[u] + oo0[u];
            oo1[u] = e1h * vh[u] + oo1[u];
          }
        }
      }
      // write valid rows to sO (fp16), kl = (tq - tqb)*32 + nh*16
      #define WRITE_ROW(OO, SS, TQ) { \
        h2 ih = bcasth(1.f / (SS)); \
        int kl = ((TQ) - tqb) * 32 + nh * 16; \
        union { h2 h[8]; uint4 u4[2]; } R; \
        _Pragma("unroll") \
        for (int u = 0; u < 8; ++u) R.h[u] = OO[u] * ih; \
        *(uint4*)&sO[loc*OSTRU + kl] = R.u4[0]; \
        *(uint4*)&sO[loc*OSTRU + kl + 8] = R.u4[1]; }
      WRITE_ROW(oo0, s0, tq0);
      if (1 < nrr) WRITE_ROW(oo1, s1, tq1);
      #undef WRITE_ROW
    }
    __syncthreads();
    // MFMA phase: kt in [0, ktn), K-offset it*512
    int ktn = it ? 9 : 16;
    const unsigned short* bcol = wctT + (size_t)ocol * 800 + it * 512 + (lane >> 4) * 8;
    for (int kt = 0; kt < ktn; ++kt) {
      h8 bfrag = *(const h8*)(bcol + kt * 32);
      h8 afrag = *(const h8*)&sO[(lane & 15)*OSTRU + kt*32 + (lane >> 4)*8];
      acc = __builtin_amdgcn_mfma_f32_16x16x32_f16(afrag, bfrag, acc, 0, 0, 0);
    }
    __syncthreads();
  }
  // epilogue: y2[loc][o] = acc + bc[o]
  float bco = bc[ocol];
  #pragma unroll
  for (int r2 = 0; r2 < 4; ++r2) {
    int loc = (lane >> 4) * 4 + r2;
    int ly = loc >> 3, lx = loc & 7;
    int gid = (b << 14) + ((h0 + ly) << 7) + (w0 + lx);
    y2[(size_t)gid * 64 + ocol] = acc[r2] + bco;
  }
}

// ---- k3: LN + MLP via MFMA f16 (GELU exact) + residual + transpose store ------------
__global__ __launch_bounds__(256) void k_mlp(
    const float* __restrict__ y2, const float* __restrict__ n2w,
    const float* __restrict__ n2b, const unsigned short* __restrict__ w1h,
    const float* __restrict__ b1, const unsigned short* __restrict__ w2h,
    const float* __restrict__ b2, float* __restrict__ out)
{
  __shared__ __align__(16) unsigned short sA[64*72];   // 9216 B  (LN'd input, fp16)
  __shared__ __align__(16) unsigned short sH[64*136];  // 17408 B (GELU output, fp16)
  int tid = threadIdx.x;
  int lane = tid & 63, wv = tid >> 6;
  int m0 = blockIdx.x * 64;
  // ---- LN: 4 threads per row
  {
    int r = tid >> 2, qd = tid & 3;
    const float* yp = y2 + (size_t)(m0 + r) * 64 + qd * 16;
    float xv[16];
    float s = 0.f;
    #pragma unroll
    for (int e = 0; e < 4; ++e) {
      float4 t4 = *(const float4*)(yp + e*4);
      xv[4*e] = t4.x; xv[4*e+1] = t4.y; xv[4*e+2] = t4.z; xv[4*e+3] = t4.w;
      s += t4.x + t4.y + t4.z + t4.w;
    }
    s += __shfl_xor(s, 1);
    s += __shfl_xor(s, 2);
    float mean = s * (1.f/64.f);
    float v = 0.f;
    #pragma unroll
    for (int e = 0; e < 16; ++e) { float d = xv[e] - mean; v = fmaf(d, d, v); }
    v += __shfl_xor(v, 1);
    v += __shfl_xor(v, 2);
    float rs = rsqrtf(v * (1.f/64.f) + 1e-5f);
    #pragma unroll
    for (int u = 0; u < 8; ++u) {
      int c0 = qd*16 + 2*u;
      float h0v = (xv[2*u]   - mean) * rs * n2w[c0]   + n2b[c0];
      float h1v = (xv[2*u+1] - mean) * rs * n2w[c0+1] + n2b[c0+1];
      *(unsigned*)&sA[r*72 + c0] = pkh2(h0v, h1v);
    }
  }
  __syncthreads();
  // ---- GEMM1: [64x64] x W1^T -> [64x128], n-slice 32 per wave
  f32x4 acc1[4][2];
  #pragma unroll
  for (int mt = 0; mt < 4; ++mt)
    #pragma unroll
    for (int nt = 0; nt < 2; ++nt) acc1[mt][nt] = (f32x4){0.f,0.f,0.f,0.f};
  #pragma unroll
  for (int kt = 0; kt < 2; ++kt) {
    #pragma unroll
    for (int nt = 0; nt < 2; ++nt) {
      int ncol = wv*32 + nt*16 + (lane & 15);
      h8 bfrag = *(const h8*)(w1h + ncol*64 + kt*32 + (lane >> 4)*8);
      #pragma unroll
      for (int mt = 0; mt < 4; ++mt) {
        h8 afrag = *(const h8*)&sA[(mt*16 + (lane & 15))*72 + kt*32 + (lane >> 4)*8];
        acc1[mt][nt] = __builtin_amdgcn_mfma_f32_16x16x32_f16(afrag, bfrag, acc1[mt][nt], 0, 0, 0);
      }
    }
  }
  // ---- bias + exact GELU -> sH (fp16)
  #pragma unroll
  for (int nt = 0; nt < 2; ++nt) {
    int ncol = wv*32 + nt*16 + (lane & 15);
    float b1v = b1[ncol];
    #pragma unroll
    for (int mt = 0; mt < 4; ++mt) {
      #pragma unroll
      for (int r2 = 0; r2 < 4; ++r2) {
        int mrow = mt*16 + (lane >> 4)*4 + r2;
        float h = acc1[mt][nt][r2] + b1v;
        float g = 0.5f * h * (1.f + erff(h * 0.70710678118f));
        sH[mrow*136 + ncol] = f2h(g);
      }
    }
  }
  __syncthreads();
  // ---- GEMM2: [64x128] x W2^T -> [64x64], n-slice 16 per wave
  f32x4 acc2[4];
  #pragma unroll
  for (int mt = 0; mt < 4; ++mt) acc2[mt] = (f32x4){0.f,0.f,0.f,0.f};
  int ocol = wv*16 + (lane & 15);
  #pragma unroll
  for (int kt = 0; kt < 4; ++kt) {
    h8 bfrag = *(const h8*)(w2h + ocol*128 + kt*32 + (lane >> 4)*8);
    #pragma unroll
    for (int mt = 0; mt < 4; ++mt) {
      h8 afrag = *(const h8*)&sH[(mt*16 + (lane & 15))*136 + kt*32 + (lane >> 4)*8];
      acc2[mt] = __builtin_amdgcn_mfma_f32_16x16x32_f16(afrag, bfrag, acc2[mt], 0, 0, 0);
    }
  }
  // ---- residual + bias + transpose store
  float b2v = b2[ocol];
  int bb = m0 >> 14;
  #pragma unroll
  for (int mt = 0; mt < 4; ++mt) {
    int mrow = mt*16 + (lane >> 4)*4;
    int l = m0 + mrow;
    const float* yp = y2 + (size_t)l * 64 + ocol;
    float4 o4;
    o4.x = yp[0]   + acc2[mt][0] + b2v;
    o4.y = yp[64]  + acc2[mt][1] + b2v;
    o4.z = yp[128] + acc2[mt][2] + b2v;
    o4.w = yp[192] + acc2[mt][3] + b2v;
    *(float4*)&out[(size_t)bb * 64 * LL + (size_t)ocol * LL + (l - (bb << 14))] = o4;
  }
}

extern "C" void kernel_launch(void* const* d_in, const int* in_sizes, int n_in,
                              void* d_out, int out_size, void* d_ws, size_t ws_size,
                              hipStream_t stream) {
  const float* x         = (const float*)d_in[0];
  const float* qkv_w     = (const float*)d_in[1];
  const float* qkv_b     = (const float*)d_in[2];
  const float* rel_table = (const float*)d_in[3];
  const float* n1w       = (const float*)d_in[4];
  const float* n1b       = (const float*)d_in[5];
  const float* n2w       = (const float*)d_in[6];
  const float* n2b       = (const float*)d_in[7];
  const float* proj_w    = (const float*)d_in[8];
  const float* proj_b    = (const float*)d_in[9];
  const float* fw        = (const float*)d_in[10];
  const float* fb        = (const float*)d_in[11];
  const float* w1        = (const float*)d_in[12];
  const float* b1        = (const float*)d_in[13];
  const float* w2        = (const float*)d_in[14];
  const float* b2        = (const float*)d_in[15];

  char* ws = (char*)d_ws;
  unsigned short* q    = (unsigned short*)(ws);                    // BL*32 fp16 = 2MB
  unsigned short* k    = (unsigned short*)(ws + 2097152);          // 2MB
  unsigned short* v    = (unsigned short*)(ws + 4194304);          // 2MB
  float*          y2   = (float*)(ws + 6291456);                   // BL*64 f32 = 8MB
  unsigned short* wctT = (unsigned short*)(ws + 14680064);         // 64*800 fp16
  float*          bc   = (float*)(ws + 14782464);                  // 64 f32
  unsigned short* w1h  = (unsigned short*)(ws + 14782720);         // 8192 fp16
  unsigned short* w2h  = (unsigned short*)(ws + 14799104);         // 8192 fp16
  float* out = (float*)d_out;

  k_combine<<<203, 256, 0, stream>>>(proj_w, proj_b, fw, fb, w1, w2, wctT, bc, w1h, w2h);
  k_ln_qkv<<<dim3(BL/128, 3), 128, 0, stream>>>(x, qkv_w, qkv_b, n1w, n1b, q, k, v);
  k_attn<<<dim3(WW/TW, HH/TH, 2), 256, 0, stream>>>(q, k, v, rel_table, wctT, bc, y2);
  k_mlp<<<BL/64, 256, 0, stream>>>(y2, n2w, n2b, w1h, b1, w2h, b2, out);
}

// Round 13
// 96.538 us; speedup vs baseline: 1.0221x; 1.0221x over previous
//
#include <hip/hip_runtime.h>
#include <cstdint>
#include <cstddef>

#define HH 128
#define WW 128
#define LL 16384   // HH*WW
#define BL 32768   // B*LL

typedef float  f32x4  __attribute__((ext_vector_type(4)));
typedef __fp16 h2     __attribute__((ext_vector_type(2)));
typedef __fp16 h8     __attribute__((ext_vector_type(8)));

union U32H { unsigned u; h2 h; };

static __device__ __forceinline__ float fdot2(h2 a, h2 b, float c) {
  return __builtin_amdgcn_fdot2(a, b, c, false);
}
static __device__ __forceinline__ unsigned pkh2(float a, float b) {
  h2 h = __builtin_amdgcn_cvt_pkrtz(a, b);
  U32H t; t.h = h; return t.u;
}
static __device__ __forceinline__ h2 bcasth(float a) {
  return __builtin_amdgcn_cvt_pkrtz(a, a);
}
static __device__ __forceinline__ unsigned short f2h(float x) {
  union { __fp16 h; unsigned short u; } c; c.h = (__fp16)x; return c.u;
}

#define LOADH8(dst, ptr) { \
  uint4 _a = *(const uint4*)(ptr); uint4 _b = *(const uint4*)((ptr)+8); U32H _t; \
  _t.u=_a.x; dst[0]=_t.h; _t.u=_a.y; dst[1]=_t.h; _t.u=_a.z; dst[2]=_t.h; _t.u=_a.w; dst[3]=_t.h; \
  _t.u=_b.x; dst[4]=_t.h; _t.u=_b.y; dst[5]=_t.h; _t.u=_b.z; dst[6]=_t.h; _t.u=_b.w; dst[7]=_t.h; }

// ---- k0: fold proj into fusion weight (fp16 B^T [64][800], kk = t*32+c); cast w1/w2 --
__global__ __launch_bounds__(256) void k_combine(
    const float* __restrict__ proj_w, const float* __restrict__ proj_b,
    const float* __restrict__ fw, const float* __restrict__ fb,
    const float* __restrict__ w1, const float* __restrict__ w2,
    unsigned short* __restrict__ wctT, float* __restrict__ bc,
    unsigned short* __restrict__ w1h, unsigned short* __restrict__ w2h)
{
  if (blockIdx.x == 200) {
    int o = threadIdx.x;
    if (o < 64) {
      float acc = proj_b[o];
      for (int m = 0; m < 64; ++m) acc = fmaf(proj_w[o*64+m], fb[m], acc);
      bc[o] = acc;
    }
    return;
  }
  if (blockIdx.x == 201) {
    for (int i = threadIdx.x; i < 8192; i += 256) w1h[i] = f2h(w1[i]);
    return;
  }
  if (blockIdx.x == 202) {
    for (int i = threadIdx.x; i < 8192; i += 256) w2h[i] = f2h(w2[i]);
    return;
  }
  int gid = blockIdx.x * 256 + threadIdx.x;   // 0..51199 = o*800 + kk
  int o  = gid / 800;
  int kk = gid - o * 800;
  int c  = kk & 31;        // de-interleaved channel (nh*16+d)
  int t  = kk >> 5;        // window position 0..24
  int in = c * 25 + t;     // fusion weight flat index
  float acc = 0.f;
  for (int m = 0; m < 64; ++m) acc = fmaf(proj_w[o*64+m], fw[m*800+in], acc);
  wctT[gid] = f2h(acc);
}

// ---- k1: LayerNorm + QKV, fp16 out, de-interleaved (c' = nh*16 + d); 3-way split ----
__global__ __launch_bounds__(128) void k_ln_qkv(
    const float* __restrict__ x, const float* __restrict__ qkv_w,
    const float* __restrict__ qkv_b, const float* __restrict__ n1w,
    const float* __restrict__ n1b, unsigned short* __restrict__ qo,
    unsigned short* __restrict__ ko, unsigned short* __restrict__ vo)
{
  __shared__ float sW[32*32];
  __shared__ float sB[32];
  __shared__ float sNw[32], sNb[32];
  int p = blockIdx.y;                         // 0=q 1=k 2=v
  for (int i = threadIdx.x; i < 32*32; i += 128) sW[i] = qkv_w[p*1024 + i];
  if (threadIdx.x < 32) {
    sB[threadIdx.x]  = qkv_b[p*32 + threadIdx.x];
    sNw[threadIdx.x] = n1w[threadIdx.x];
    sNb[threadIdx.x] = n1b[threadIdx.x];
  }
  __syncthreads();
  int gid = blockIdx.x * 128 + threadIdx.x;   // 0..BL-1
  int b = gid >> 14, l = gid & (LL - 1);
  const float* xp = x + (size_t)b * 32 * LL + l;
  float xv[32];
  float mean = 0.f;
  #pragma unroll
  for (int c = 0; c < 32; ++c) { xv[c] = xp[(size_t)c * LL]; mean += xv[c]; }
  mean *= 0.03125f;
  float var = 0.f;
  #pragma unroll
  for (int c = 0; c < 32; ++c) { float d = xv[c] - mean; var = fmaf(d, d, var); }
  float rs = rsqrtf(var * 0.03125f + 1e-5f);
  #pragma unroll
  for (int c = 0; c < 32; ++c) xv[c] = (xv[c] - mean) * rs * sNw[c] + sNb[c];
  float ao[32];
  #pragma unroll
  for (int o = 0; o < 32; ++o) {
    const float* wr = &sW[o * 32];
    float acc = sB[o];
    #pragma unroll
    for (int c = 0; c < 32; ++c) acc = fmaf(xv[c], wr[c], acc);
    ao[(o & 1) * 16 + (o >> 1)] = acc;        // de-interleave heads
  }
  unsigned short* op = (p == 0 ? qo : p == 1 ? ko : vo) + (size_t)gid * 32;
  #pragma unroll
  for (int e = 0; e < 4; ++e) {
    uint4 pk4;
    pk4.x = pkh2(ao[e*8+0], ao[e*8+1]);
    pk4.y = pkh2(ao[e*8+2], ao[e*8+3]);
    pk4.z = pkh2(ao[e*8+4], ao[e*8+5]);
    pk4.w = pkh2(ao[e*8+6], ao[e*8+7]);
    *(uint4*)(op + e*8) = pk4;
  }
}

// ---- k2: tiled windowed attention (fused QK-exp-PV, tq-QUAD, split chains) ----------
// Block = 4x8 = 32 locations, 256 threads (4 waves). 2 compute + 2 MFMA phases (r9 shape).
#define TH 4
#define TW 8
#define NPOS 96   // 8x12 halo
#define KVSTR 24  // per-head fp16 row stride in ushorts (48B; 16 data + pad)
#define OSTRU 524 // sO row stride (ushorts): 512 kk + 12 pad

__global__ __launch_bounds__(256, 3) void k_attn(
    const unsigned short* __restrict__ qi, const unsigned short* __restrict__ ki,
    const unsigned short* __restrict__ vi, const float* __restrict__ rel_table,
    const unsigned short* __restrict__ wctT, const float* __restrict__ bc,
    float* __restrict__ y2)
{
  __shared__ __align__(16) unsigned short sQ[192*KVSTR]; // 9216 B  ([nh*96+pos][16+pad])
  __shared__ __align__(16) unsigned short sK[192*KVSTR]; // 9216 B
  __shared__ __align__(16) unsigned short sV[192*KVSTR]; // 9216 B
  __shared__ __align__(16) unsigned short sO[32*OSTRU];  // 33536 B
  __shared__ float sRT[162];
  __shared__ float sPar[NPOS];

  int tid = threadIdx.x;
  int lane = tid & 63, wv = tid >> 6;
  int b  = blockIdx.z;
  int h0 = blockIdx.y * TH, w0 = blockIdx.x * TW;

  for (int i = tid; i < 162; i += 256) sRT[i] = rel_table[i];
  if (tid < NPOS) {
    int ph = tid / 12, pw = tid - ph * 12;
    int h2v = h0 + ph - 2, w2v = w0 + pw - 2;
    bool valid = ((unsigned)h2v < HH) && ((unsigned)w2v < WW);
    sPar[tid] = (valid && (((h2v + w2v) & 1) == 1)) ? 1.f : 0.f;
  }
  // halo staging: 3 arrays x 96 pos x 2 nh x 2 half-chunks(16B) = 1152 units
  for (int idx = tid; idx < 1152; idx += 256) {
    int arr = idx / 384;                  // 0=K, 1=V, 2=Q
    int rem = idx - arr * 384;
    int pos = rem >> 2, q4 = rem & 3;
    int nh = q4 >> 1, half = q4 & 1;
    int ph = pos / 12, pw = pos - ph * 12;
    int h2v = h0 + ph - 2, w2v = w0 + pw - 2;
    uint4 val = make_uint4(0u, 0u, 0u, 0u);
    if (((unsigned)h2v < HH) && ((unsigned)w2v < WW)) {
      const unsigned short* src = (arr == 0 ? ki : arr == 1 ? vi : qi)
                       + ((size_t)((b << 14) + (h2v << 7) + w2v)) * 32 + nh * 16 + half * 8;
      val = *(const uint4*)src;
    }
    unsigned short* dp = (arr == 0 ? sK : arr == 1 ? sV : sQ)
                       + (nh * 96 + pos) * KVSTR + half * 8;
    *(uint4*)dp = val;
  }
  __syncthreads();

  f32x4 acc[2] = {{0.f,0.f,0.f,0.f},{0.f,0.f,0.f,0.f}};
  int ocol = wv * 16 + (lane & 15);

  for (int it = 0; it < 2; ++it) {
    int g = wv * 2 + (lane >> 5);             // 0..7, half-wave uniform
    int qd = it * 4 + (g >> 1);               // quad index 0..7 (valid <7)
    int nh = g & 1;
    int nhb = nh * 96;
    if (qd < 7) {
      int nrr = (qd < 6) ? 4 : 1;             // valid rows in quad (tq<=24)
      int loc = lane & 31;
      int ly = loc >> 3, lx = loc & 7;
      int posb = ly * 12 + lx;
      int tqb = 4 * qd;
      int tq0 = tqb, tq1 = tqb+1, tq2 = tqb+2, tq3 = tqb+3;
      int iq0 = tq0/5, jq0 = tq0 - iq0*5;
      int iq1 = tq1/5, jq1 = tq1 - iq1*5;
      int iq2 = tq2/5, jq2 = tq2 - iq2*5;
      int iq3 = tq3/5, jq3 = tq3 - iq3*5;
      int pq0 = posb + iq0*12 + jq0; pq0 = pq0 > 95 ? 95 : pq0;
      int pq1 = posb + iq1*12 + jq1; pq1 = pq1 > 95 ? 95 : pq1;
      int pq2 = posb + iq2*12 + jq2; pq2 = pq2 > 95 ? 95 : pq2;
      int pq3 = posb + iq3*12 + jq3; pq3 = pq3 > 95 ? 95 : pq3;
      float parq0 = sPar[pq0], parq1 = sPar[pq1], parq2 = sPar[pq2], parq3 = sPar[pq3];
      h2 q0[8], q1[8], q2[8], q3[8];
      LOADH8(q0, &sQ[(nhb+pq0)*KVSTR]);
      LOADH8(q1, &sQ[(nhb+pq1)*KVSTR]);
      LOADH8(q2, &sQ[(nhb+pq2)*KVSTR]);
      LOADH8(q3, &sQ[(nhb+pq3)*KVSTR]);
      float s0 = 0.f, s1 = 0.f, s2 = 0.f, s3 = 0.f;
      h2 oo0[8], oo1[8], oo2[8], oo3[8];
      #pragma unroll
      for (int e = 0; e < 8; ++e) {
        oo0[e] = (h2)(__fp16)0.f; oo1[e] = (h2)(__fp16)0.f;
        oo2[e] = (h2)(__fp16)0.f; oo3[e] = (h2)(__fp16)0.f;
      }
      #pragma unroll 1
      for (int ik = 0; ik < 5; ++ik) {
        int rb0 = ((iq0-ik+4)*9 + jq0 + 4)*2 + nh;
        int rb1 = ((iq1-ik+4)*9 + jq1 + 4)*2 + nh;
        int rb2 = ((iq2-ik+4)*9 + jq2 + 4)*2 + nh;
        int rb3 = ((iq3-ik+4)*9 + jq3 + 4)*2 + nh;
        #pragma unroll
        for (int jk = 0; jk < 5; ++jk) {
          int pk = posb + ik*12 + jk;
          h2 kh[8];
          LOADH8(kh, &sK[(nhb+pk)*KVSTR]);
          float park = sPar[pk];
          float mk = (park == 1.f) ? 0.f : -100.f;
          // split chains: 2 independent depth-4 chains per row
          float a0a=0.f, a0b=0.f, a1a=0.f, a1b=0.f;
          float a2a=0.f, a2b=0.f, a3a=0.f, a3b=0.f;
          #pragma unroll
          for (int u = 0; u < 4; ++u) {
            a0a = fdot2(q0[u], kh[u], a0a);
            a1a = fdot2(q1[u], kh[u], a1a);
            a2a = fdot2(q2[u], kh[u], a2a);
            a3a = fdot2(q3[u], kh[u], a3a);
            a0b = fdot2(q0[u+4], kh[u+4], a0b);
            a1b = fdot2(q1[u+4], kh[u+4], a1b);
            a2b = fdot2(q2[u+4], kh[u+4], a2b);
            a3b = fdot2(q3[u+4], kh[u+4], a3b);
          }
          float a0 = a0a + a0b, a1 = a1a + a1b, a2 = a2a + a2b, a3 = a3a + a3b;
          int i0 = rb0 - 2*jk; i0 = i0 > 161 ? 161 : i0;
          int i1 = rb1 - 2*jk; i1 = i1 > 161 ? 161 : i1;
          int i2 = rb2 - 2*jk; i2 = i2 > 161 ? 161 : i2;
          int i3 = rb3 - 2*jk; i3 = i3 > 161 ? 161 : i3;
          float e0 = __expf(fmaf(parq0, mk, fmaf(a0, 0.25f, sRT[i0])));
          float e1 = __expf(fmaf(parq1, mk, fmaf(a1, 0.25f, sRT[i1])));
          float e2 = __expf(fmaf(parq2, mk, fmaf(a2, 0.25f, sRT[i2])));
          float e3 = __expf(fmaf(parq3, mk, fmaf(a3, 0.25f, sRT[i3])));
          s0 += e0; s1 += e1; s2 += e2; s3 += e3;
          h2 e0h = bcasth(e0), e1h = bcasth(e1), e2h = bcasth(e2), e3h = bcasth(e3);
          h2 vh[8];
          LOADH8(vh, &sV[(nhb+pk)*KVSTR]);
          #pragma unroll
          for (int u = 0; u < 8; ++u) {
            oo0[u] = e0h * vh[u] + oo0[u];
            oo1[u] = e1h * vh[u] + oo1[u];
            oo2[u] = e2h * vh[u] + oo2[u];
            oo3[u] = e3h * vh[u] + oo3[u];
          }
        }
      }
      // write valid rows to sO (fp16), kl = (tq - it*16)*32 + nh*16
      #define WRITE_ROW(OO, SS, TQ) { \
        h2 ih = bcasth(1.f / (SS)); \
        int kl = ((TQ) - it*16) * 32 + nh * 16; \
        union { h2 h[8]; uint4 u4[2]; } R; \
        _Pragma("unroll") \
        for (int u = 0; u < 8; ++u) R.h[u] = OO[u] * ih; \
        *(uint4*)&sO[loc*OSTRU + kl] = R.u4[0]; \
        *(uint4*)&sO[loc*OSTRU + kl + 8] = R.u4[1]; }
      WRITE_ROW(oo0, s0, tq0);
      if (1 < nrr) {
        WRITE_ROW(oo1, s1, tq1);
        WRITE_ROW(oo2, s2, tq2);
        WRITE_ROW(oo3, s3, tq3);
      }
      #undef WRITE_ROW
    }
    __syncthreads();
    // MFMA phase: kt in [0, ktn), K-offset it*512
    int ktn = it ? 9 : 16;
    const unsigned short* bcol = wctT + (size_t)ocol * 800 + it * 512 + (lane >> 4) * 8;
    for (int kt = 0; kt < ktn; ++kt) {
      h8 bfrag = *(const h8*)(bcol + kt * 32);
      #pragma unroll
      for (int mt = 0; mt < 2; ++mt) {
        h8 afrag = *(const h8*)&sO[(mt*16 + (lane & 15))*OSTRU + kt*32 + (lane >> 4)*8];
        acc[mt] = __builtin_amdgcn_mfma_f32_16x16x32_f16(afrag, bfrag, acc[mt], 0, 0, 0);
      }
    }
    __syncthreads();
  }
  // epilogue: y2[loc][o] = acc + bc[o]
  float bco = bc[ocol];
  #pragma unroll
  for (int mt = 0; mt < 2; ++mt) {
    #pragma unroll
    for (int r2 = 0; r2 < 4; ++r2) {
      int loc = mt * 16 + (lane >> 4) * 4 + r2;
      int ly = loc >> 3, lx = loc & 7;
      int gid = (b << 14) + ((h0 + ly) << 7) + (w0 + lx);
      y2[(size_t)gid * 64 + ocol] = acc[mt][r2] + bco;
    }
  }
}

// ---- k3: LN + MLP via MFMA f16 (GELU exact) + residual + transpose store ------------
__global__ __launch_bounds__(256) void k_mlp(
    const float* __restrict__ y2, const float* __restrict__ n2w,
    const float* __restrict__ n2b, const unsigned short* __restrict__ w1h,
    const float* __restrict__ b1, const unsigned short* __restrict__ w2h,
    const float* __restrict__ b2, float* __restrict__ out)
{
  __shared__ __align__(16) unsigned short sA[64*72];   // 9216 B  (LN'd input, fp16)
  __shared__ __align__(16) unsigned short sH[64*136];  // 17408 B (GELU output, fp16)
  int tid = threadIdx.x;
  int lane = tid & 63, wv = tid >> 6;
  int m0 = blockIdx.x * 64;
  // ---- LN: 4 threads per row
  {
    int r = tid >> 2, qd = tid & 3;
    const float* yp = y2 + (size_t)(m0 + r) * 64 + qd * 16;
    float xv[16];
    float s = 0.f;
    #pragma unroll
    for (int e = 0; e < 4; ++e) {
      float4 t4 = *(const float4*)(yp + e*4);
      xv[4*e] = t4.x; xv[4*e+1] = t4.y; xv[4*e+2] = t4.z; xv[4*e+3] = t4.w;
      s += t4.x + t4.y + t4.z + t4.w;
    }
    s += __shfl_xor(s, 1);
    s += __shfl_xor(s, 2);
    float mean = s * (1.f/64.f);
    float v = 0.f;
    #pragma unroll
    for (int e = 0; e < 16; ++e) { float d = xv[e] - mean; v = fmaf(d, d, v); }
    v += __shfl_xor(v, 1);
    v += __shfl_xor(v, 2);
    float rs = rsqrtf(v * (1.f/64.f) + 1e-5f);
    #pragma unroll
    for (int u = 0; u < 8; ++u) {
      int c0 = qd*16 + 2*u;
      float h0v = (xv[2*u]   - mean) * rs * n2w[c0]   + n2b[c0];
      float h1v = (xv[2*u+1] - mean) * rs * n2w[c0+1] + n2b[c0+1];
      *(unsigned*)&sA[r*72 + c0] = pkh2(h0v, h1v);
    }
  }
  __syncthreads();
  // ---- GEMM1: [64x64] x W1^T -> [64x128], n-slice 32 per wave
  f32x4 acc1[4][2];
  #pragma unroll
  for (int mt = 0; mt < 4; ++mt)
    #pragma unroll
    for (int nt = 0; nt < 2; ++nt) acc1[mt][nt] = (f32x4){0.f,0.f,0.f,0.f};
  #pragma unroll
  for (int kt = 0; kt < 2; ++kt) {
    #pragma unroll
    for (int nt = 0; nt < 2; ++nt) {
      int ncol = wv*32 + nt*16 + (lane & 15);
      h8 bfrag = *(const h8*)(w1h + ncol*64 + kt*32 + (lane >> 4)*8);
      #pragma unroll
      for (int mt = 0; mt < 4; ++mt) {
        h8 afrag = *(const h8*)&sA[(mt*16 + (lane & 15))*72 + kt*32 + (lane >> 4)*8];
        acc1[mt][nt] = __builtin_amdgcn_mfma_f32_16x16x32_f16(afrag, bfrag, acc1[mt][nt], 0, 0, 0);
      }
    }
  }
  // ---- bias + exact GELU -> sH (fp16)
  #pragma unroll
  for (int nt = 0; nt < 2; ++nt) {
    int ncol = wv*32 + nt*16 + (lane & 15);
    float b1v = b1[ncol];
    #pragma unroll
    for (int mt = 0; mt < 4; ++mt) {
      #pragma unroll
      for (int r2 = 0; r2 < 4; ++r2) {
        int mrow = mt*16 + (lane >> 4)*4 + r2;
        float h = acc1[mt][nt][r2] + b1v;
        float g = 0.5f * h * (1.f + erff(h * 0.70710678118f));
        sH[mrow*136 + ncol] = f2h(g);
      }
    }
  }
  __syncthreads();
  // ---- GEMM2: [64x128] x W2^T -> [64x64], n-slice 16 per wave
  f32x4 acc2[4];
  #pragma unroll
  for (int mt = 0; mt < 4; ++mt) acc2[mt] = (f32x4){0.f,0.f,0.f,0.f};
  int ocol = wv*16 + (lane & 15);
  #pragma unroll
  for (int kt = 0; kt < 4; ++kt) {
    h8 bfrag = *(const h8*)(w2h + ocol*128 + kt*32 + (lane >> 4)*8);
    #pragma unroll
    for (int mt = 0; mt < 4; ++mt) {
      h8 afrag = *(const h8*)&sH[(mt*16 + (lane & 15))*136 + kt*32 + (lane >> 4)*8];
      acc2[mt] = __builtin_amdgcn_mfma_f32_16x16x32_f16(afrag, bfrag, acc2[mt], 0, 0, 0);
    }
  }
  // ---- residual + bias + transpose store
  float b2v = b2[ocol];
  int bb = m0 >> 14;
  #pragma unroll
  for (int mt = 0; mt < 4; ++mt) {
    int mrow = mt*16 + (lane >> 4)*4;
    int l = m0 + mrow;
    const float* yp = y2 + (size_t)l * 64 + ocol;
    float4 o4;
    o4.x = yp[0]   + acc2[mt][0] + b2v;
    o4.y = yp[64]  + acc2[mt][1] + b2v;
    o4.z = yp[128] + acc2[mt][2] + b2v;
    o4.w = yp[192] + acc2[mt][3] + b2v;
    *(float4*)&out[(size_t)bb * 64 * LL + (size_t)ocol * LL + (l - (bb << 14))] = o4;
  }
}

extern "C" void kernel_launch(void* const* d_in, const int* in_sizes, int n_in,
                              void* d_out, int out_size, void* d_ws, size_t ws_size,
                              hipStream_t stream) {
  const float* x         = (const float*)d_in[0];
  const float* qkv_w     = (const float*)d_in[1];
  const float* qkv_b     = (const float*)d_in[2];
  const float* rel_table = (const float*)d_in[3];
  const float* n1w       = (const float*)d_in[4];
  const float* n1b       = (const float*)d_in[5];
  const float* n2w       = (const float*)d_in[6];
  const float* n2b       = (const float*)d_in[7];
  const float* proj_w    = (const float*)d_in[8];
  const float* proj_b    = (const float*)d_in[9];
  const float* fw        = (const float*)d_in[10];
  const float* fb        = (const float*)d_in[11];
  const float* w1        = (const float*)d_in[12];
  const float* b1        = (const float*)d_in[13];
  const float* w2        = (const float*)d_in[14];
  const float* b2        = (const float*)d_in[15];

  char* ws = (char*)d_ws;
  unsigned short* q    = (unsigned short*)(ws);                    // BL*32 fp16 = 2MB
  unsigned short* k    = (unsigned short*)(ws + 2097152);          // 2MB
  unsigned short* v    = (unsigned short*)(ws + 4194304);          // 2MB
  float*          y2   = (float*)(ws + 6291456);                   // BL*64 f32 = 8MB
  unsigned short* wctT = (unsigned short*)(ws + 14680064);         // 64*800 fp16
  float*          bc   = (float*)(ws + 14782464);                  // 64 f32
  unsigned short* w1h  = (unsigned short*)(ws + 14782720);         // 8192 fp16
  unsigned short* w2h  = (unsigned short*)(ws + 14799104);         // 8192 fp16
  float* out = (float*)d_out;

  k_combine<<<203, 256, 0, stream>>>(proj_w, proj_b, fw, fb, w1, w2, wctT, bc, w1h, w2h);
  k_ln_qkv<<<dim3(BL/128, 3), 128, 0, stream>>>(x, qkv_w, qkv_b, n1w, n1b, q, k, v);
  k_attn<<<dim3(WW/TW, HH/TH, 2), 256, 0, stream>>>(q, k, v, rel_table, wctT, bc, y2);
  k_mlp<<<BL/64, 256, 0, stream>>>(y2, n2w, n2b, w1h, b1, w2h, b2, out);
}

// Round 14
// 92.797 us; speedup vs baseline: 1.0633x; 1.0403x over previous
//
#include <hip/hip_runtime.h>
#include <cstdint>
#include <cstddef>

#define HH 128
#define WW 128
#define LL 16384   // HH*WW
#define BL 32768   // B*LL

typedef float  f32x4  __attribute__((ext_vector_type(4)));
typedef __fp16 h2     __attribute__((ext_vector_type(2)));
typedef __fp16 h8     __attribute__((ext_vector_type(8)));

union U32H { unsigned u; h2 h; };

static __device__ __forceinline__ float fdot2(h2 a, h2 b, float c) {
  return __builtin_amdgcn_fdot2(a, b, c, false);
}
static __device__ __forceinline__ unsigned pkh2(float a, float b) {
  h2 h = __builtin_amdgcn_cvt_pkrtz(a, b);
  U32H t; t.h = h; return t.u;
}
static __device__ __forceinline__ h2 bcasth(float a) {
  return __builtin_amdgcn_cvt_pkrtz(a, a);
}
static __device__ __forceinline__ unsigned short f2h(float x) {
  union { __fp16 h; unsigned short u; } c; c.h = (__fp16)x; return c.u;
}

#define LOADH8(dst, ptr) { \
  uint4 _a = *(const uint4*)(ptr); uint4 _b = *(const uint4*)((ptr)+8); U32H _t; \
  _t.u=_a.x; dst[0]=_t.h; _t.u=_a.y; dst[1]=_t.h; _t.u=_a.z; dst[2]=_t.h; _t.u=_a.w; dst[3]=_t.h; \
  _t.u=_b.x; dst[4]=_t.h; _t.u=_b.y; dst[5]=_t.h; _t.u=_b.z; dst[6]=_t.h; _t.u=_b.w; dst[7]=_t.h; }

// ---- k0: fold proj into fusion weight (fp16 B^T [64][800], kk = t*32+c); cast w1/w2 --
__global__ __launch_bounds__(256) void k_combine(
    const float* __restrict__ proj_w, const float* __restrict__ proj_b,
    const float* __restrict__ fw, const float* __restrict__ fb,
    const float* __restrict__ w1, const float* __restrict__ w2,
    unsigned short* __restrict__ wctT, float* __restrict__ bc,
    unsigned short* __restrict__ w1h, unsigned short* __restrict__ w2h)
{
  if (blockIdx.x == 200) {
    int o = threadIdx.x;
    if (o < 64) {
      float acc = proj_b[o];
      for (int m = 0; m < 64; ++m) acc = fmaf(proj_w[o*64+m], fb[m], acc);
      bc[o] = acc;
    }
    return;
  }
  if (blockIdx.x == 201) {
    for (int i = threadIdx.x; i < 8192; i += 256) w1h[i] = f2h(w1[i]);
    return;
  }
  if (blockIdx.x == 202) {
    for (int i = threadIdx.x; i < 8192; i += 256) w2h[i] = f2h(w2[i]);
    return;
  }
  int gid = blockIdx.x * 256 + threadIdx.x;   // 0..51199 = o*800 + kk
  int o  = gid / 800;
  int kk = gid - o * 800;
  int c  = kk & 31;        // de-interleaved channel (nh*16+d)
  int t  = kk >> 5;        // window position 0..24
  int in = c * 25 + t;     // fusion weight flat index
  float acc = 0.f;
  for (int m = 0; m < 64; ++m) acc = fmaf(proj_w[o*64+m], fw[m*800+in], acc);
  wctT[gid] = f2h(acc);
}

// ---- k1: LayerNorm + QKV, fp16 out, de-interleaved (c' = nh*16 + d); 3-way split ----
__global__ __launch_bounds__(128) void k_ln_qkv(
    const float* __restrict__ x, const float* __restrict__ qkv_w,
    const float* __restrict__ qkv_b, const float* __restrict__ n1w,
    const float* __restrict__ n1b, unsigned short* __restrict__ qo,
    unsigned short* __restrict__ ko, unsigned short* __restrict__ vo)
{
  __shared__ float sW[32*32];
  __shared__ float sB[32];
  __shared__ float sNw[32], sNb[32];
  int p = blockIdx.y;                         // 0=q 1=k 2=v
  for (int i = threadIdx.x; i < 32*32; i += 128) sW[i] = qkv_w[p*1024 + i];
  if (threadIdx.x < 32) {
    sB[threadIdx.x]  = qkv_b[p*32 + threadIdx.x];
    sNw[threadIdx.x] = n1w[threadIdx.x];
    sNb[threadIdx.x] = n1b[threadIdx.x];
  }
  __syncthreads();
  int gid = blockIdx.x * 128 + threadIdx.x;   // 0..BL-1
  int b = gid >> 14, l = gid & (LL - 1);
  const float* xp = x + (size_t)b * 32 * LL + l;
  float xv[32];
  float mean = 0.f;
  #pragma unroll
  for (int c = 0; c < 32; ++c) { xv[c] = xp[(size_t)c * LL]; mean += xv[c]; }
  mean *= 0.03125f;
  float var = 0.f;
  #pragma unroll
  for (int c = 0; c < 32; ++c) { float d = xv[c] - mean; var = fmaf(d, d, var); }
  float rs = rsqrtf(var * 0.03125f + 1e-5f);
  #pragma unroll
  for (int c = 0; c < 32; ++c) xv[c] = (xv[c] - mean) * rs * sNw[c] + sNb[c];
  float ao[32];
  #pragma unroll
  for (int o = 0; o < 32; ++o) {
    const float* wr = &sW[o * 32];
    float acc = sB[o];
    #pragma unroll
    for (int c = 0; c < 32; ++c) acc = fmaf(xv[c], wr[c], acc);
    ao[(o & 1) * 16 + (o >> 1)] = acc;        // de-interleave heads
  }
  unsigned short* op = (p == 0 ? qo : p == 1 ? ko : vo) + (size_t)gid * 32;
  #pragma unroll
  for (int e = 0; e < 4; ++e) {
    uint4 pk4;
    pk4.x = pkh2(ao[e*8+0], ao[e*8+1]);
    pk4.y = pkh2(ao[e*8+2], ao[e*8+3]);
    pk4.z = pkh2(ao[e*8+4], ao[e*8+5]);
    pk4.w = pkh2(ao[e*8+6], ao[e*8+7]);
    *(uint4*)(op + e*8) = pk4;
  }
}

// ---- k2: tiled windowed attention, PARITY-SCHEDULED pairs + MFMA f16 fusion GEMM ----
#define TH 4
#define TW 8
#define NPOS 96   // 8x12 halo
#define KVSTR 24  // per-head fp16 row stride in ushorts (48B; 16 data + pad)
#define OSTRU 524 // sO row stride (ushorts): 512 kk + 12 pad

// MODE: 0 = LONG fast (parq=0, mask-free), 1 = SHORT fast cls0 (ik+jk odd),
//       2 = SHORT fast cls1 (ik+jk even), 3 = LONG slow (full mask logic)
template<int MODE>
static __device__ __forceinline__ void attn_pair(
    int tqA, int tqB, int nh, bool wA, bool wB,
    int posb, int sOrow, int klbase,
    const unsigned short* __restrict__ sQ, const unsigned short* __restrict__ sK,
    const unsigned short* __restrict__ sV, unsigned short* __restrict__ sO,
    const float* __restrict__ sRT, const float* __restrict__ sPar)
{
  const int nhb = nh * 96;
  int iqA = tqA / 5, jqA = tqA - iqA * 5;
  int iqB = tqB / 5, jqB = tqB - iqB * 5;
  int pqA = posb + iqA * 12 + jqA;
  int pqB = posb + iqB * 12 + jqB;
  float parqA = 0.f, parqB = 0.f;
  if (MODE == 3) { parqA = sPar[pqA]; parqB = sPar[pqB]; }
  h2 qA[8], qB[8];
  LOADH8(qA, &sQ[(nhb + pqA) * KVSTR]);
  LOADH8(qB, &sQ[(nhb + pqB) * KVSTR]);
  const int bbA = (iqA * 9 + jqA) * 2 + 80 + nh;
  const int bbB = (iqB * 9 + jqB) * 2 + 80 + nh;
  float sA = 0.f, sB = 0.f;
  h2 ooA[8], ooB[8];
  #pragma unroll
  for (int e = 0; e < 8; ++e) { ooA[e] = (h2)(__fp16)0.f; ooB[e] = (h2)(__fp16)0.f; }
  #pragma unroll 1
  for (int ik = 0; ik < 5; ++ik) {
    int pkrow = posb + ik * 12;
    int bA = bbA - ik * 18, bB = bbB - ik * 18;
    auto body = [&](int jk) {
      int pk = pkrow + jk;
      h2 kh[8];
      LOADH8(kh, &sK[(nhb + pk) * KVSTR]);
      float aA = 0.f, aB = 0.f;
      #pragma unroll
      for (int u = 0; u < 8; ++u) { aA = fdot2(qA[u], kh[u], aA); aB = fdot2(qB[u], kh[u], aB); }
      float biasA = sRT[bA - 2 * jk], biasB = sRT[bB - 2 * jk];
      float eA, eB;
      if (MODE == 3) {
        float park = sPar[pk];
        float mk = (park == 1.f) ? 0.f : -100.f;
        eA = __expf(fmaf(parqA, mk, fmaf(aA, 0.25f, biasA)));
        eB = __expf(fmaf(parqB, mk, fmaf(aB, 0.25f, biasB)));
      } else {
        eA = __expf(fmaf(aA, 0.25f, biasA));
        eB = __expf(fmaf(aB, 0.25f, biasB));
      }
      sA += eA; sB += eB;
      h2 eAh = bcasth(eA), eBh = bcasth(eB);
      h2 vh[8];
      LOADH8(vh, &sV[(nhb + pk) * KVSTR]);
      #pragma unroll
      for (int u = 0; u < 8; ++u) { ooA[u] = eAh * vh[u] + ooA[u]; ooB[u] = eBh * vh[u] + ooB[u]; }
    };
    if (MODE == 0 || MODE == 3) {
      body(0); body(1); body(2); body(3); body(4);
    } else if (MODE == 1) {                 // need (ik+jk) odd
      if ((ik & 1) == 0) { body(1); body(3); }
      else { body(0); body(2); body(4); }
    } else {                                // MODE 2: need (ik+jk) even
      if ((ik & 1) == 0) { body(0); body(2); body(4); }
      else { body(1); body(3); }
    }
  }
  if (wA) {
    h2 ih = bcasth(1.f / sA);
    int kl = (tqA - klbase) * 32 + nh * 16;
    union { h2 h[8]; uint4 u4[2]; } R;
    #pragma unroll
    for (int u = 0; u < 8; ++u) R.h[u] = ooA[u] * ih;
    *(uint4*)&sO[sOrow * OSTRU + kl] = R.u4[0];
    *(uint4*)&sO[sOrow * OSTRU + kl + 8] = R.u4[1];
  }
  if (wB) {
    h2 ih = bcasth(1.f / sB);
    int kl = (tqB - klbase) * 32 + nh * 16;
    union { h2 h[8]; uint4 u4[2]; } R;
    #pragma unroll
    for (int u = 0; u < 8; ++u) R.h[u] = ooB[u] * ih;
    *(uint4*)&sO[sOrow * OSTRU + kl] = R.u4[0];
    *(uint4*)&sO[sOrow * OSTRU + kl + 8] = R.u4[1];
  }
}

__global__ __launch_bounds__(256, 3) void k_attn(
    const unsigned short* __restrict__ qi, const unsigned short* __restrict__ ki,
    const unsigned short* __restrict__ vi, const float* __restrict__ rel_table,
    const unsigned short* __restrict__ wctT, const float* __restrict__ bc,
    float* __restrict__ y2)
{
  __shared__ __align__(16) unsigned short sQ[192*KVSTR]; // 9216 B  ([nh*96+pos][16+pad])
  __shared__ __align__(16) unsigned short sK[192*KVSTR]; // 9216 B
  __shared__ __align__(16) unsigned short sV[192*KVSTR]; // 9216 B
  __shared__ __align__(16) unsigned short sO[32*OSTRU];  // 33536 B
  __shared__ float sRT[162];
  __shared__ float sPar[NPOS];

  int tid = threadIdx.x;
  int lane = tid & 63, wv = tid >> 6;
  int b  = blockIdx.z;
  int h0 = blockIdx.y * TH, w0 = blockIdx.x * TW;
  bool fastb = (blockIdx.y >= 1) && (blockIdx.y <= 30) && (blockIdx.x >= 1) && (blockIdx.x <= 14);

  for (int i = tid; i < 162; i += 256) sRT[i] = rel_table[i];
  if (tid < NPOS) {
    int ph = tid / 12, pw = tid - ph * 12;
    int h2v = h0 + ph - 2, w2v = w0 + pw - 2;
    bool valid = ((unsigned)h2v < HH) && ((unsigned)w2v < WW);
    sPar[tid] = (valid && (((h2v + w2v) & 1) == 1)) ? 1.f : 0.f;
  }
  // halo staging: 3 arrays x 96 pos x 2 nh x 2 half-chunks(16B) = 1152 units
  for (int idx = tid; idx < 1152; idx += 256) {
    int arr = idx / 384;                  // 0=K, 1=V, 2=Q
    int rem = idx - arr * 384;
    int pos = rem >> 2, q4 = rem & 3;
    int nh = q4 >> 1, half = q4 & 1;
    int ph = pos / 12, pw = pos - ph * 12;
    int h2v = h0 + ph - 2, w2v = w0 + pw - 2;
    uint4 val = make_uint4(0u, 0u, 0u, 0u);
    if (((unsigned)h2v < HH) && ((unsigned)w2v < WW)) {
      const unsigned short* src = (arr == 0 ? ki : arr == 1 ? vi : qi)
                       + ((size_t)((b << 14) + (h2v << 7) + w2v)) * 32 + nh * 16 + half * 8;
      val = *(const uint4*)src;
    }
    unsigned short* dp = (arr == 0 ? sK : arr == 1 ? sV : sQ)
                       + (nh * 96 + pos) * KVSTR + half * 8;
    *(uint4*)dp = val;
  }
  __syncthreads();

  f32x4 acc[2] = {{0.f,0.f,0.f,0.f},{0.f,0.f,0.f,0.f}};
  int ocol = wv * 16 + (lane & 15);

  // parity-major task geometry
  int cls = wv & 1;                         // wave-uniform class
  int l16 = lane & 15;
  int nh  = wv >> 1;                        // waves 0,1 -> nh0 ; 2,3 -> nh1
  int kk4 = lane >> 4;                      // 0..3 task slot within wave
  int ly  = l16 >> 2;
  int lx  = 2 * (l16 & 3) + ((cls + ly) & 1);
  int posb  = ly * 12 + lx;
  int sOrow = cls * 16 + l16;

  // ---- phase 0: rows tq 0..15
  if (fastb) {
    if (cls == 0) {
      attn_pair<0>(4*kk4,   4*kk4+2, nh, true, true, posb, sOrow, 0, sQ, sK, sV, sO, sRT, sPar);
      attn_pair<1>(4*kk4+1, 4*kk4+3, nh, true, true, posb, sOrow, 0, sQ, sK, sV, sO, sRT, sPar);
    } else {
      attn_pair<0>(4*kk4+1, 4*kk4+3, nh, true, true, posb, sOrow, 0, sQ, sK, sV, sO, sRT, sPar);
      attn_pair<2>(4*kk4,   4*kk4+2, nh, true, true, posb, sOrow, 0, sQ, sK, sV, sO, sRT, sPar);
    }
  } else {
    attn_pair<3>(4*kk4,   4*kk4+2, nh, true, true, posb, sOrow, 0, sQ, sK, sV, sO, sRT, sPar);
    attn_pair<3>(4*kk4+1, 4*kk4+3, nh, true, true, posb, sOrow, 0, sQ, sK, sV, sO, sRT, sPar);
  }
  __syncthreads();
  {
    const unsigned short* bcol = wctT + (size_t)ocol * 800 + (lane >> 4) * 8;
    for (int kt = 0; kt < 16; ++kt) {
      h8 bfrag = *(const h8*)(bcol + kt * 32);
      #pragma unroll
      for (int mt = 0; mt < 2; ++mt) {
        h8 afrag = *(const h8*)&sO[(mt*16 + (lane & 15))*OSTRU + kt*32 + (lane >> 4)*8];
        acc[mt] = __builtin_amdgcn_mfma_f32_16x16x32_f16(afrag, bfrag, acc[mt], 0, 0, 0);
      }
    }
  }
  __syncthreads();

  // ---- phase 1: rows tq 16..24 (dummy-padded, write-flags control)
  {
    int LqA = 16, LqB = 18; bool LwA = false, LwB = false;
    int SqA = 17, SqB = 19; bool SwA = false, SwB = false;
    if (cls == 0) {
      if (kk4 == 0)      { LwA = LwB = true; SwA = SwB = true; }
      else if (kk4 == 1) { LqA = 20; LqB = 22; LwA = LwB = true; SqA = 21; SqB = 23; SwA = SwB = true; }
      else if (kk4 == 2) { LqA = 24; LqB = 24; LwA = true; }
    } else {
      if (kk4 == 0)      { LqA = 17; LqB = 19; LwA = LwB = true; SqA = 16; SqB = 18; SwA = SwB = true; }
      else if (kk4 == 1) { LqA = 21; LqB = 23; LwA = LwB = true; SqA = 20; SqB = 22; SwA = SwB = true; }
      else if (kk4 == 2) { SqA = 24; SqB = 24; SwA = true; }
    }
    if (fastb) {
      if (cls == 0) {
        attn_pair<0>(LqA, LqB, nh, LwA, LwB, posb, sOrow, 16, sQ, sK, sV, sO, sRT, sPar);
        attn_pair<1>(SqA, SqB, nh, SwA, SwB, posb, sOrow, 16, sQ, sK, sV, sO, sRT, sPar);
      } else {
        attn_pair<0>(LqA, LqB, nh, LwA, LwB, posb, sOrow, 16, sQ, sK, sV, sO, sRT, sPar);
        attn_pair<2>(SqA, SqB, nh, SwA, SwB, posb, sOrow, 16, sQ, sK, sV, sO, sRT, sPar);
      }
    } else {
      attn_pair<3>(LqA, LqB, nh, LwA, LwB, posb, sOrow, 16, sQ, sK, sV, sO, sRT, sPar);
      attn_pair<3>(SqA, SqB, nh, SwA, SwB, posb, sOrow, 16, sQ, sK, sV, sO, sRT, sPar);
    }
  }
  __syncthreads();
  {
    const unsigned short* bcol = wctT + (size_t)ocol * 800 + 512 + (lane >> 4) * 8;
    for (int kt = 0; kt < 9; ++kt) {
      h8 bfrag = *(const h8*)(bcol + kt * 32);
      #pragma unroll
      for (int mt = 0; mt < 2; ++mt) {
        h8 afrag = *(const h8*)&sO[(mt*16 + (lane & 15))*OSTRU + kt*32 + (lane >> 4)*8];
        acc[mt] = __builtin_amdgcn_mfma_f32_16x16x32_f16(afrag, bfrag, acc[mt], 0, 0, 0);
      }
    }
  }
  __syncthreads();

  // epilogue: y2[loc][o] = acc + bc[o]; row mapping is class-major
  float bco = bc[ocol];
  #pragma unroll
  for (int mt = 0; mt < 2; ++mt) {
    #pragma unroll
    for (int r2 = 0; r2 < 4; ++r2) {
      int ly2 = lane >> 4;
      int lx2 = 2 * r2 + ((mt + ly2) & 1);
      int gid = (b << 14) + ((h0 + ly2) << 7) + (w0 + lx2);
      y2[(size_t)gid * 64 + ocol] = acc[mt][r2] + bco;
    }
  }
}

// ---- k3: LN + MLP via MFMA f16 (GELU exact) + residual + transpose store ------------
__global__ __launch_bounds__(256) void k_mlp(
    const float* __restrict__ y2, const float* __restrict__ n2w,
    const float* __restrict__ n2b, const unsigned short* __restrict__ w1h,
    const float* __restrict__ b1, const unsigned short* __restrict__ w2h,
    const float* __restrict__ b2, float* __restrict__ out)
{
  __shared__ __align__(16) unsigned short sA[64*72];   // 9216 B  (LN'd input, fp16)
  __shared__ __align__(16) unsigned short sH[64*136];  // 17408 B (GELU output, fp16)
  int tid = threadIdx.x;
  int lane = tid & 63, wv = tid >> 6;
  int m0 = blockIdx.x * 64;
  // ---- LN: 4 threads per row
  {
    int r = tid >> 2, qd = tid & 3;
    const float* yp = y2 + (size_t)(m0 + r) * 64 + qd * 16;
    float xv[16];
    float s = 0.f;
    #pragma unroll
    for (int e = 0; e < 4; ++e) {
      float4 t4 = *(const float4*)(yp + e*4);
      xv[4*e] = t4.x; xv[4*e+1] = t4.y; xv[4*e+2] = t4.z; xv[4*e+3] = t4.w;
      s += t4.x + t4.y + t4.z + t4.w;
    }
    s += __shfl_xor(s, 1);
    s += __shfl_xor(s, 2);
    float mean = s * (1.f/64.f);
    float v = 0.f;
    #pragma unroll
    for (int e = 0; e < 16; ++e) { float d = xv[e] - mean; v = fmaf(d, d, v); }
    v += __shfl_xor(v, 1);
    v += __shfl_xor(v, 2);
    float rs = rsqrtf(v * (1.f/64.f) + 1e-5f);
    #pragma unroll
    for (int u = 0; u < 8; ++u) {
      int c0 = qd*16 + 2*u;
      float h0v = (xv[2*u]   - mean) * rs * n2w[c0]   + n2b[c0];
      float h1v = (xv[2*u+1] - mean) * rs * n2w[c0+1] + n2b[c0+1];
      *(unsigned*)&sA[r*72 + c0] = pkh2(h0v, h1v);
    }
  }
  __syncthreads();
  // ---- GEMM1: [64x64] x W1^T -> [64x128], n-slice 32 per wave
  f32x4 acc1[4][2];
  #pragma unroll
  for (int mt = 0; mt < 4; ++mt)
    #pragma unroll
    for (int nt = 0; nt < 2; ++nt) acc1[mt][nt] = (f32x4){0.f,0.f,0.f,0.f};
  #pragma unroll
  for (int kt = 0; kt < 2; ++kt) {
    #pragma unroll
    for (int nt = 0; nt < 2; ++nt) {
      int ncol = wv*32 + nt*16 + (lane & 15);
      h8 bfrag = *(const h8*)(w1h + ncol*64 + kt*32 + (lane >> 4)*8);
      #pragma unroll
      for (int mt = 0; mt < 4; ++mt) {
        h8 afrag = *(const h8*)&sA[(mt*16 + (lane & 15))*72 + kt*32 + (lane >> 4)*8];
        acc1[mt][nt] = __builtin_amdgcn_mfma_f32_16x16x32_f16(afrag, bfrag, acc1[mt][nt], 0, 0, 0);
      }
    }
  }
  // ---- bias + exact GELU -> sH (fp16)
  #pragma unroll
  for (int nt = 0; nt < 2; ++nt) {
    int ncol = wv*32 + nt*16 + (lane & 15);
    float b1v = b1[ncol];
    #pragma unroll
    for (int mt = 0; mt < 4; ++mt) {
      #pragma unroll
      for (int r2 = 0; r2 < 4; ++r2) {
        int mrow = mt*16 + (lane >> 4)*4 + r2;
        float h = acc1[mt][nt][r2] + b1v;
        float g = 0.5f * h * (1.f + erff(h * 0.70710678118f));
        sH[mrow*136 + ncol] = f2h(g);
      }
    }
  }
  __syncthreads();
  // ---- GEMM2: [64x128] x W2^T -> [64x64], n-slice 16 per wave
  f32x4 acc2[4];
  #pragma unroll
  for (int mt = 0; mt < 4; ++mt) acc2[mt] = (f32x4){0.f,0.f,0.f,0.f};
  int ocol = wv*16 + (lane & 15);
  #pragma unroll
  for (int kt = 0; kt < 4; ++kt) {
    h8 bfrag = *(const h8*)(w2h + ocol*128 + kt*32 + (lane >> 4)*8);
    #pragma unroll
    for (int mt = 0; mt < 4; ++mt) {
      h8 afrag = *(const h8*)&sH[(mt*16 + (lane & 15))*136 + kt*32 + (lane >> 4)*8];
      acc2[mt] = __builtin_amdgcn_mfma_f32_16x16x32_f16(afrag, bfrag, acc2[mt], 0, 0, 0);
    }
  }
  // ---- residual + bias + transpose store
  float b2v = b2[ocol];
  int bb = m0 >> 14;
  #pragma unroll
  for (int mt = 0; mt < 4; ++mt) {
    int mrow = mt*16 + (lane >> 4)*4;
    int l = m0 + mrow;
    const float* yp = y2 + (size_t)l * 64 + ocol;
    float4 o4;
    o4.x = yp[0]   + acc2[mt][0] + b2v;
    o4.y = yp[64]  + acc2[mt][1] + b2v;
    o4.z = yp[128] + acc2[mt][2] + b2v;
    o4.w = yp[192] + acc2[mt][3] + b2v;
    *(float4*)&out[(size_t)bb * 64 * LL + (size_t)ocol * LL + (l - (bb << 14))] = o4;
  }
}

extern "C" void kernel_launch(void* const* d_in, const int* in_sizes, int n_in,
                              void* d_out, int out_size, void* d_ws, size_t ws_size,
                              hipStream_t stream) {
  const float* x         = (const float*)d_in[0];
  const float* qkv_w     = (const float*)d_in[1];
  const float* qkv_b     = (const float*)d_in[2];
  const float* rel_table = (const float*)d_in[3];
  const float* n1w       = (const float*)d_in[4];
  const float* n1b       = (const float*)d_in[5];
  const float* n2w       = (const float*)d_in[6];
  const float* n2b       = (const float*)d_in[7];
  const float* proj_w    = (const float*)d_in[8];
  const float* proj_b    = (const float*)d_in[9];
  const float* fw        = (const float*)d_in[10];
  const float* fb        = (const float*)d_in[11];
  const float* w1        = (const float*)d_in[12];
  const float* b1        = (const float*)d_in[13];
  const float* w2        = (const float*)d_in[14];
  const float* b2        = (const float*)d_in[15];

  char* ws = (char*)d_ws;
  unsigned short* q    = (unsigned short*)(ws);                    // BL*32 fp16 = 2MB
  unsigned short* k    = (unsigned short*)(ws + 2097152);          // 2MB
  unsigned short* v    = (unsigned short*)(ws + 4194304);          // 2MB
  float*          y2   = (float*)(ws + 6291456);                   // BL*64 f32 = 8MB
  unsigned short* wctT = (unsigned short*)(ws + 14680064);         // 64*800 fp16
  float*          bc   = (float*)(ws + 14782464);                  // 64 f32
  unsigned short* w1h  = (unsigned short*)(ws + 14782720);         // 8192 fp16
  unsigned short* w2h  = (unsigned short*)(ws + 14799104);         // 8192 fp16
  float* out = (float*)d_out;

  k_combine<<<203, 256, 0, stream>>>(proj_w, proj_b, fw, fb, w1, w2, wctT, bc, w1h, w2h);
  k_ln_qkv<<<dim3(BL/128, 3), 128, 0, stream>>>(x, qkv_w, qkv_b, n1w, n1b, q, k, v);
  k_attn<<<dim3(WW/TW, HH/TH, 2), 256, 0, stream>>>(q, k, v, rel_table, wctT, bc, y2);
  k_mlp<<<BL/64, 256, 0, stream>>>(y2, n2w, n2b, w1h, b1, w2h, b2, out);
}

// Round 15
// 88.810 us; speedup vs baseline: 1.1110x; 1.0449x over previous
//
#include <hip/hip_runtime.h>
#include <cstdint>
#include <cstddef>

#define HH 128
#define WW 128
#define LL 16384   // HH*WW
#define BL 32768   // B*LL

typedef float  f32x4  __attribute__((ext_vector_type(4)));
typedef __fp16 h2     __attribute__((ext_vector_type(2)));
typedef __fp16 h8     __attribute__((ext_vector_type(8)));

union U32H { unsigned u; h2 h; };

static __device__ __forceinline__ float fdot2(h2 a, h2 b, float c) {
  return __builtin_amdgcn_fdot2(a, b, c, false);
}
static __device__ __forceinline__ unsigned pkh2(float a, float b) {
  h2 h = __builtin_amdgcn_cvt_pkrtz(a, b);
  U32H t; t.h = h; return t.u;
}
static __device__ __forceinline__ h2 bcasth(float a) {
  return __builtin_amdgcn_cvt_pkrtz(a, a);
}
static __device__ __forceinline__ unsigned short f2h(float x) {
  union { __fp16 h; unsigned short u; } c; c.h = (__fp16)x; return c.u;
}

#define LOADH8(dst, ptr) { \
  uint4 _a = *(const uint4*)(ptr); uint4 _b = *(const uint4*)((ptr)+8); U32H _t; \
  _t.u=_a.x; dst[0]=_t.h; _t.u=_a.y; dst[1]=_t.h; _t.u=_a.z; dst[2]=_t.h; _t.u=_a.w; dst[3]=_t.h; \
  _t.u=_b.x; dst[4]=_t.h; _t.u=_b.y; dst[5]=_t.h; _t.u=_b.z; dst[6]=_t.h; _t.u=_b.w; dst[7]=_t.h; }

// ---- k0: fold proj into fusion weight (fp16 B^T [64][800], kk = t*32+c); cast w1/w2 --
__global__ __launch_bounds__(256) void k_combine(
    const float* __restrict__ proj_w, const float* __restrict__ proj_b,
    const float* __restrict__ fw, const float* __restrict__ fb,
    const float* __restrict__ w1, const float* __restrict__ w2,
    unsigned short* __restrict__ wctT, float* __restrict__ bc,
    unsigned short* __restrict__ w1h, unsigned short* __restrict__ w2h)
{
  if (blockIdx.x == 200) {
    int o = threadIdx.x;
    if (o < 64) {
      float acc = proj_b[o];
      for (int m = 0; m < 64; ++m) acc = fmaf(proj_w[o*64+m], fb[m], acc);
      bc[o] = acc;
    }
    return;
  }
  if (blockIdx.x == 201) {
    for (int i = threadIdx.x; i < 8192; i += 256) w1h[i] = f2h(w1[i]);
    return;
  }
  if (blockIdx.x == 202) {
    for (int i = threadIdx.x; i < 8192; i += 256) w2h[i] = f2h(w2[i]);
    return;
  }
  int gid = blockIdx.x * 256 + threadIdx.x;   // 0..51199 = o*800 + kk
  int o  = gid / 800;
  int kk = gid - o * 800;
  int c  = kk & 31;        // de-interleaved channel (nh*16+d)
  int t  = kk >> 5;        // window position 0..24
  int in = c * 25 + t;     // fusion weight flat index
  float acc = 0.f;
  for (int m = 0; m < 64; ++m) acc = fmaf(proj_w[o*64+m], fw[m*800+in], acc);
  wctT[gid] = f2h(acc);
}

// ---- k1: LayerNorm + QKV, fp16 out, de-interleaved (c' = nh*16 + d); 3-way split ----
__global__ __launch_bounds__(128) void k_ln_qkv(
    const float* __restrict__ x, const float* __restrict__ qkv_w,
    const float* __restrict__ qkv_b, const float* __restrict__ n1w,
    const float* __restrict__ n1b, unsigned short* __restrict__ qo,
    unsigned short* __restrict__ ko, unsigned short* __restrict__ vo)
{
  __shared__ float sW[32*32];
  __shared__ float sB[32];
  __shared__ float sNw[32], sNb[32];
  int p = blockIdx.y;                         // 0=q 1=k 2=v
  for (int i = threadIdx.x; i < 32*32; i += 128) sW[i] = qkv_w[p*1024 + i];
  if (threadIdx.x < 32) {
    sB[threadIdx.x]  = qkv_b[p*32 + threadIdx.x];
    sNw[threadIdx.x] = n1w[threadIdx.x];
    sNb[threadIdx.x] = n1b[threadIdx.x];
  }
  __syncthreads();
  int gid = blockIdx.x * 128 + threadIdx.x;   // 0..BL-1
  int b = gid >> 14, l = gid & (LL - 1);
  const float* xp = x + (size_t)b * 32 * LL + l;
  float xv[32];
  float mean = 0.f;
  #pragma unroll
  for (int c = 0; c < 32; ++c) { xv[c] = xp[(size_t)c * LL]; mean += xv[c]; }
  mean *= 0.03125f;
  float var = 0.f;
  #pragma unroll
  for (int c = 0; c < 32; ++c) { float d = xv[c] - mean; var = fmaf(d, d, var); }
  float rs = rsqrtf(var * 0.03125f + 1e-5f);
  #pragma unroll
  for (int c = 0; c < 32; ++c) xv[c] = (xv[c] - mean) * rs * sNw[c] + sNb[c];
  float ao[32];
  #pragma unroll
  for (int o = 0; o < 32; ++o) {
    const float* wr = &sW[o * 32];
    float acc = sB[o];
    #pragma unroll
    for (int c = 0; c < 32; ++c) acc = fmaf(xv[c], wr[c], acc);
    ao[(o & 1) * 16 + (o >> 1)] = acc;        // de-interleave heads
  }
  unsigned short* op = (p == 0 ? qo : p == 1 ? ko : vo) + (size_t)gid * 32;
  #pragma unroll
  for (int e = 0; e < 4; ++e) {
    uint4 pk4;
    pk4.x = pkh2(ao[e*8+0], ao[e*8+1]);
    pk4.y = pkh2(ao[e*8+2], ao[e*8+3]);
    pk4.z = pkh2(ao[e*8+4], ao[e*8+5]);
    pk4.w = pkh2(ao[e*8+6], ao[e*8+7]);
    *(uint4*)(op + e*8) = pk4;
  }
}

// ---- k2: tiled windowed attention, PARITY-SCHEDULED pairs, Q direct from L2 ---------
#define TH 4
#define TW 8
#define NPOS 96   // 8x12 halo
#define KVSTR 24  // per-head fp16 row stride in ushorts (48B; 16 data + pad)
#define OSTRU 524 // sO row stride (ushorts): 512 kk + 12 pad

// MODE: 0 = LONG fast (parq=0, mask-free), 1 = SHORT fast cls0 (ik+jk odd),
//       2 = SHORT fast cls1 (ik+jk even), 3 = LONG slow (full mask logic)
template<int MODE>
static __device__ __forceinline__ void attn_pair(
    int tqA, int tqB, int nh, bool wA, bool wB,
    int h0, int w0, int ly, int lx, int b,
    const unsigned short* __restrict__ qi,
    int posb, int sOrow, int klbase,
    const unsigned short* __restrict__ sK,
    const unsigned short* __restrict__ sV, unsigned short* __restrict__ sO,
    const float* __restrict__ sRT, const float* __restrict__ sPar)
{
  const int nhb = nh * 96;
  int iqA = tqA / 5, jqA = tqA - iqA * 5;
  int iqB = tqB / 5, jqB = tqB - iqB * 5;
  int hqA = h0 + ly + iqA - 2, wqA = w0 + lx + jqA - 2;
  int hqB = h0 + ly + iqB - 2, wqB = w0 + lx + jqB - 2;
  h2 qA[8], qB[8];
  float parqA = 0.f, parqB = 0.f;
  if (MODE == 3) {
    bool vA = ((unsigned)hqA < HH) && ((unsigned)wqA < WW);
    bool vB = ((unsigned)hqB < HH) && ((unsigned)wqB < WW);
    parqA = (vA && (((hqA + wqA) & 1) == 1)) ? 1.f : 0.f;
    parqB = (vB && (((hqB + wqB) & 1) == 1)) ? 1.f : 0.f;
    if (vA) { LOADH8(qA, qi + ((size_t)((b<<14)+(hqA<<7)+wqA))*32 + nh*16); }
    else {
      #pragma unroll
      for (int u = 0; u < 8; ++u) qA[u] = (h2)(__fp16)0.f;
    }
    if (vB) { LOADH8(qB, qi + ((size_t)((b<<14)+(hqB<<7)+wqB))*32 + nh*16); }
    else {
      #pragma unroll
      for (int u = 0; u < 8; ++u) qB[u] = (h2)(__fp16)0.f;
    }
  } else {
    LOADH8(qA, qi + ((size_t)((b<<14)+(hqA<<7)+wqA))*32 + nh*16);
    LOADH8(qB, qi + ((size_t)((b<<14)+(hqB<<7)+wqB))*32 + nh*16);
  }
  const int bbA = (iqA * 9 + jqA) * 2 + 80 + nh;
  const int bbB = (iqB * 9 + jqB) * 2 + 80 + nh;
  float sA = 0.f, sB = 0.f;
  h2 ooA[8], ooB[8];
  #pragma unroll
  for (int e = 0; e < 8; ++e) { ooA[e] = (h2)(__fp16)0.f; ooB[e] = (h2)(__fp16)0.f; }
  #pragma unroll 1
  for (int ik = 0; ik < 5; ++ik) {
    int pkrow = posb + ik * 12;
    int bA = bbA - ik * 18, bB = bbB - ik * 18;
    auto body = [&](int jk) {
      int pk = pkrow + jk;
      h2 kh[8];
      LOADH8(kh, &sK[(nhb + pk) * KVSTR]);
      float aA = 0.f, aB = 0.f;
      #pragma unroll
      for (int u = 0; u < 8; ++u) { aA = fdot2(qA[u], kh[u], aA); aB = fdot2(qB[u], kh[u], aB); }
      float biasA = sRT[bA - 2 * jk], biasB = sRT[bB - 2 * jk];
      float eA, eB;
      if (MODE == 3) {
        float park = sPar[pk];
        float mk = (park == 1.f) ? 0.f : -100.f;
        eA = __expf(fmaf(parqA, mk, fmaf(aA, 0.25f, biasA)));
        eB = __expf(fmaf(parqB, mk, fmaf(aB, 0.25f, biasB)));
      } else {
        eA = __expf(fmaf(aA, 0.25f, biasA));
        eB = __expf(fmaf(aB, 0.25f, biasB));
      }
      sA += eA; sB += eB;
      h2 eAh = bcasth(eA), eBh = bcasth(eB);
      h2 vh[8];
      LOADH8(vh, &sV[(nhb + pk) * KVSTR]);
      #pragma unroll
      for (int u = 0; u < 8; ++u) { ooA[u] = eAh * vh[u] + ooA[u]; ooB[u] = eBh * vh[u] + ooB[u]; }
    };
    if (MODE == 0 || MODE == 3) {
      body(0); body(1); body(2); body(3); body(4);
    } else if (MODE == 1) {                 // need (ik+jk) odd
      if ((ik & 1) == 0) { body(1); body(3); }
      else { body(0); body(2); body(4); }
    } else {                                // MODE 2: need (ik+jk) even
      if ((ik & 1) == 0) { body(0); body(2); body(4); }
      else { body(1); body(3); }
    }
  }
  if (wA) {
    h2 ih = bcasth(1.f / sA);
    int kl = (tqA - klbase) * 32 + nh * 16;
    union { h2 h[8]; uint4 u4[2]; } R;
    #pragma unroll
    for (int u = 0; u < 8; ++u) R.h[u] = ooA[u] * ih;
    *(uint4*)&sO[sOrow * OSTRU + kl] = R.u4[0];
    *(uint4*)&sO[sOrow * OSTRU + kl + 8] = R.u4[1];
  }
  if (wB) {
    h2 ih = bcasth(1.f / sB);
    int kl = (tqB - klbase) * 32 + nh * 16;
    union { h2 h[8]; uint4 u4[2]; } R;
    #pragma unroll
    for (int u = 0; u < 8; ++u) R.h[u] = ooB[u] * ih;
    *(uint4*)&sO[sOrow * OSTRU + kl] = R.u4[0];
    *(uint4*)&sO[sOrow * OSTRU + kl + 8] = R.u4[1];
  }
}

__global__ __launch_bounds__(256, 3) void k_attn(
    const unsigned short* __restrict__ qi, const unsigned short* __restrict__ ki,
    const unsigned short* __restrict__ vi, const float* __restrict__ rel_table,
    const unsigned short* __restrict__ wctT, const float* __restrict__ bc,
    float* __restrict__ y2)
{
  __shared__ __align__(16) unsigned short sK[192*KVSTR]; // 9216 B
  __shared__ __align__(16) unsigned short sV[192*KVSTR]; // 9216 B
  __shared__ __align__(16) unsigned short sO[32*OSTRU];  // 33536 B
  __shared__ float sRT[162];
  __shared__ float sPar[NPOS];
  // total ~53.0 KB -> 3 blocks/CU

  int tid = threadIdx.x;
  int lane = tid & 63, wv = tid >> 6;
  int b  = blockIdx.z;
  int h0 = blockIdx.y * TH, w0 = blockIdx.x * TW;
  bool fastb = (blockIdx.y >= 1) && (blockIdx.y <= 30) && (blockIdx.x >= 1) && (blockIdx.x <= 14);

  for (int i = tid; i < 162; i += 256) sRT[i] = rel_table[i];
  if (tid < NPOS) {
    int ph = tid / 12, pw = tid - ph * 12;
    int h2v = h0 + ph - 2, w2v = w0 + pw - 2;
    bool valid = ((unsigned)h2v < HH) && ((unsigned)w2v < WW);
    sPar[tid] = (valid && (((h2v + w2v) & 1) == 1)) ? 1.f : 0.f;
  }
  // halo staging: K,V only: 2 arrays x 96 pos x 2 nh x 2 half-chunks(16B) = 768 units
  for (int idx = tid; idx < 768; idx += 256) {
    int arr = idx / 384;                  // 0=K, 1=V
    int rem = idx - arr * 384;
    int pos = rem >> 2, q4 = rem & 3;
    int nh = q4 >> 1, half = q4 & 1;
    int ph = pos / 12, pw = pos - ph * 12;
    int h2v = h0 + ph - 2, w2v = w0 + pw - 2;
    uint4 val = make_uint4(0u, 0u, 0u, 0u);
    if (((unsigned)h2v < HH) && ((unsigned)w2v < WW)) {
      const unsigned short* src = (arr == 0 ? ki : vi)
                       + ((size_t)((b << 14) + (h2v << 7) + w2v)) * 32 + nh * 16 + half * 8;
      val = *(const uint4*)src;
    }
    unsigned short* dp = (arr == 0 ? sK : sV) + (nh * 96 + pos) * KVSTR + half * 8;
    *(uint4*)dp = val;
  }
  __syncthreads();

  f32x4 acc[2] = {{0.f,0.f,0.f,0.f},{0.f,0.f,0.f,0.f}};
  int ocol = wv * 16 + (lane & 15);

  // parity-major task geometry
  int cls = wv & 1;                         // wave-uniform class
  int l16 = lane & 15;
  int nh  = wv >> 1;                        // waves 0,1 -> nh0 ; 2,3 -> nh1
  int kk4 = lane >> 4;                      // 0..3 task slot within wave
  int ly  = l16 >> 2;
  int lx  = 2 * (l16 & 3) + ((cls + ly) & 1);
  int posb  = ly * 12 + lx;
  int sOrow = cls * 16 + l16;

  // ---- phase 0: rows tq 0..15
  if (fastb) {
    if (cls == 0) {
      attn_pair<0>(4*kk4,   4*kk4+2, nh, true, true, h0,w0,ly,lx,b,qi, posb, sOrow, 0, sK, sV, sO, sRT, sPar);
      attn_pair<1>(4*kk4+1, 4*kk4+3, nh, true, true, h0,w0,ly,lx,b,qi, posb, sOrow, 0, sK, sV, sO, sRT, sPar);
    } else {
      attn_pair<0>(4*kk4+1, 4*kk4+3, nh, true, true, h0,w0,ly,lx,b,qi, posb, sOrow, 0, sK, sV, sO, sRT, sPar);
      attn_pair<2>(4*kk4,   4*kk4+2, nh, true, true, h0,w0,ly,lx,b,qi, posb, sOrow, 0, sK, sV, sO, sRT, sPar);
    }
  } else {
    attn_pair<3>(4*kk4,   4*kk4+2, nh, true, true, h0,w0,ly,lx,b,qi, posb, sOrow, 0, sK, sV, sO, sRT, sPar);
    attn_pair<3>(4*kk4+1, 4*kk4+3, nh, true, true, h0,w0,ly,lx,b,qi, posb, sOrow, 0, sK, sV, sO, sRT, sPar);
  }
  __syncthreads();
  {
    const unsigned short* bcol = wctT + (size_t)ocol * 800 + (lane >> 4) * 8;
    for (int kt = 0; kt < 16; ++kt) {
      h8 bfrag = *(const h8*)(bcol + kt * 32);
      #pragma unroll
      for (int mt = 0; mt < 2; ++mt) {
        h8 afrag = *(const h8*)&sO[(mt*16 + (lane & 15))*OSTRU + kt*32 + (lane >> 4)*8];
        acc[mt] = __builtin_amdgcn_mfma_f32_16x16x32_f16(afrag, bfrag, acc[mt], 0, 0, 0);
      }
    }
  }
  __syncthreads();

  // ---- phase 1: rows tq 16..24 (dummy-padded, write-flags control)
  {
    int LqA = 16, LqB = 18; bool LwA = false, LwB = false;
    int SqA = 17, SqB = 19; bool SwA = false, SwB = false;
    if (cls == 0) {
      if (kk4 == 0)      { LwA = LwB = true; SwA = SwB = true; }
      else if (kk4 == 1) { LqA = 20; LqB = 22; LwA = LwB = true; SqA = 21; SqB = 23; SwA = SwB = true; }
      else if (kk4 == 2) { LqA = 24; LqB = 24; LwA = true; }
    } else {
      if (kk4 == 0)      { LqA = 17; LqB = 19; LwA = LwB = true; SqA = 16; SqB = 18; SwA = SwB = true; }
      else if (kk4 == 1) { LqA = 21; LqB = 23; LwA = LwB = true; SqA = 20; SqB = 22; SwA = SwB = true; }
      else if (kk4 == 2) { SqA = 24; SqB = 24; SwA = true; }
    }
    if (fastb) {
      if (cls == 0) {
        attn_pair<0>(LqA, LqB, nh, LwA, LwB, h0,w0,ly,lx,b,qi, posb, sOrow, 16, sK, sV, sO, sRT, sPar);
        attn_pair<1>(SqA, SqB, nh, SwA, SwB, h0,w0,ly,lx,b,qi, posb, sOrow, 16, sK, sV, sO, sRT, sPar);
      } else {
        attn_pair<0>(LqA, LqB, nh, LwA, LwB, h0,w0,ly,lx,b,qi, posb, sOrow, 16, sK, sV, sO, sRT, sPar);
        attn_pair<2>(SqA, SqB, nh, SwA, SwB, h0,w0,ly,lx,b,qi, posb, sOrow, 16, sK, sV, sO, sRT, sPar);
      }
    } else {
      attn_pair<3>(LqA, LqB, nh, LwA, LwB, h0,w0,ly,lx,b,qi, posb, sOrow, 16, sK, sV, sO, sRT, sPar);
      attn_pair<3>(SqA, SqB, nh, SwA, SwB, h0,w0,ly,lx,b,qi, posb, sOrow, 16, sK, sV, sO, sRT, sPar);
    }
  }
  __syncthreads();
  {
    const unsigned short* bcol = wctT + (size_t)ocol * 800 + 512 + (lane >> 4) * 8;
    for (int kt = 0; kt < 9; ++kt) {
      h8 bfrag = *(const h8*)(bcol + kt * 32);
      #pragma unroll
      for (int mt = 0; mt < 2; ++mt) {
        h8 afrag = *(const h8*)&sO[(mt*16 + (lane & 15))*OSTRU + kt*32 + (lane >> 4)*8];
        acc[mt] = __builtin_amdgcn_mfma_f32_16x16x32_f16(afrag, bfrag, acc[mt], 0, 0, 0);
      }
    }
  }
  __syncthreads();

  // epilogue: y2[loc][o] = acc + bc[o]; row mapping is class-major
  float bco = bc[ocol];
  #pragma unroll
  for (int mt = 0; mt < 2; ++mt) {
    #pragma unroll
    for (int r2 = 0; r2 < 4; ++r2) {
      int ly2 = lane >> 4;
      int lx2 = 2 * r2 + ((mt + ly2) & 1);
      int gid = (b << 14) + ((h0 + ly2) << 7) + (w0 + lx2);
      y2[(size_t)gid * 64 + ocol] = acc[mt][r2] + bco;
    }
  }
}

// ---- k3: LN + MLP via MFMA f16 (GELU exact) + residual + transpose store ------------
__global__ __launch_bounds__(256) void k_mlp(
    const float* __restrict__ y2, const float* __restrict__ n2w,
    const float* __restrict__ n2b, const unsigned short* __restrict__ w1h,
    const float* __restrict__ b1, const unsigned short* __restrict__ w2h,
    const float* __restrict__ b2, float* __restrict__ out)
{
  __shared__ __align__(16) unsigned short sA[64*72];   // 9216 B  (LN'd input, fp16)
  __shared__ __align__(16) unsigned short sH[64*136];  // 17408 B (GELU output, fp16)
  int tid = threadIdx.x;
  int lane = tid & 63, wv = tid >> 6;
  int m0 = blockIdx.x * 64;
  // ---- LN: 4 threads per row
  {
    int r = tid >> 2, qd = tid & 3;
    const float* yp = y2 + (size_t)(m0 + r) * 64 + qd * 16;
    float xv[16];
    float s = 0.f;
    #pragma unroll
    for (int e = 0; e < 4; ++e) {
      float4 t4 = *(const float4*)(yp + e*4);
      xv[4*e] = t4.x; xv[4*e+1] = t4.y; xv[4*e+2] = t4.z; xv[4*e+3] = t4.w;
      s += t4.x + t4.y + t4.z + t4.w;
    }
    s += __shfl_xor(s, 1);
    s += __shfl_xor(s, 2);
    float mean = s * (1.f/64.f);
    float v = 0.f;
    #pragma unroll
    for (int e = 0; e < 16; ++e) { float d = xv[e] - mean; v = fmaf(d, d, v); }
    v += __shfl_xor(v, 1);
    v += __shfl_xor(v, 2);
    float rs = rsqrtf(v * (1.f/64.f) + 1e-5f);
    #pragma unroll
    for (int u = 0; u < 8; ++u) {
      int c0 = qd*16 + 2*u;
      float h0v = (xv[2*u]   - mean) * rs * n2w[c0]   + n2b[c0];
      float h1v = (xv[2*u+1] - mean) * rs * n2w[c0+1] + n2b[c0+1];
      *(unsigned*)&sA[r*72 + c0] = pkh2(h0v, h1v);
    }
  }
  __syncthreads();
  // ---- GEMM1: [64x64] x W1^T -> [64x128], n-slice 32 per wave
  f32x4 acc1[4][2];
  #pragma unroll
  for (int mt = 0; mt < 4; ++mt)
    #pragma unroll
    for (int nt = 0; nt < 2; ++nt) acc1[mt][nt] = (f32x4){0.f,0.f,0.f,0.f};
  #pragma unroll
  for (int kt = 0; kt < 2; ++kt) {
    #pragma unroll
    for (int nt = 0; nt < 2; ++nt) {
      int ncol = wv*32 + nt*16 + (lane & 15);
      h8 bfrag = *(const h8*)(w1h + ncol*64 + kt*32 + (lane >> 4)*8);
      #pragma unroll
      for (int mt = 0; mt < 4; ++mt) {
        h8 afrag = *(const h8*)&sA[(mt*16 + (lane & 15))*72 + kt*32 + (lane >> 4)*8];
        acc1[mt][nt] = __builtin_amdgcn_mfma_f32_16x16x32_f16(afrag, bfrag, acc1[mt][nt], 0, 0, 0);
      }
    }
  }
  // ---- bias + exact GELU -> sH (fp16)
  #pragma unroll
  for (int nt = 0; nt < 2; ++nt) {
    int ncol = wv*32 + nt*16 + (lane & 15);
    float b1v = b1[ncol];
    #pragma unroll
    for (int mt = 0; mt < 4; ++mt) {
      #pragma unroll
      for (int r2 = 0; r2 < 4; ++r2) {
        int mrow = mt*16 + (lane >> 4)*4 + r2;
        float h = acc1[mt][nt][r2] + b1v;
        float g = 0.5f * h * (1.f + erff(h * 0.70710678118f));
        sH[mrow*136 + ncol] = f2h(g);
      }
    }
  }
  __syncthreads();
  // ---- GEMM2: [64x128] x W2^T -> [64x64], n-slice 16 per wave
  f32x4 acc2[4];
  #pragma unroll
  for (int mt = 0; mt < 4; ++mt) acc2[mt] = (f32x4){0.f,0.f,0.f,0.f};
  int ocol = wv*16 + (lane & 15);
  #pragma unroll
  for (int kt = 0; kt < 4; ++kt) {
    h8 bfrag = *(const h8*)(w2h + ocol*128 + kt*32 + (lane >> 4)*8);
    #pragma unroll
    for (int mt = 0; mt < 4; ++mt) {
      h8 afrag = *(const h8*)&sH[(mt*16 + (lane & 15))*136 + kt*32 + (lane >> 4)*8];
      acc2[mt] = __builtin_amdgcn_mfma_f32_16x16x32_f16(afrag, bfrag, acc2[mt], 0, 0, 0);
    }
  }
  // ---- residual + bias + transpose store
  float b2v = b2[ocol];
  int bb = m0 >> 14;
  #pragma unroll
  for (int mt = 0; mt < 4; ++mt) {
    int mrow = mt*16 + (lane >> 4)*4;
    int l = m0 + mrow;
    const float* yp = y2 + (size_t)l * 64 + ocol;
    float4 o4;
    o4.x = yp[0]   + acc2[mt][0] + b2v;
    o4.y = yp[64]  + acc2[mt][1] + b2v;
    o4.z = yp[128] + acc2[mt][2] + b2v;
    o4.w = yp[192] + acc2[mt][3] + b2v;
    *(float4*)&out[(size_t)bb * 64 * LL + (size_t)ocol * LL + (l - (bb << 14))] = o4;
  }
}

extern "C" void kernel_launch(void* const* d_in, const int* in_sizes, int n_in,
                              void* d_out, int out_size, void* d_ws, size_t ws_size,
                              hipStream_t stream) {
  const float* x         = (const float*)d_in[0];
  const float* qkv_w     = (const float*)d_in[1];
  const float* qkv_b     = (const float*)d_in[2];
  const float* rel_table = (const float*)d_in[3];
  const float* n1w       = (const float*)d_in[4];
  const float* n1b       = (const float*)d_in[5];
  const float* n2w       = (const float*)d_in[6];
  const float* n2b       = (const float*)d_in[7];
  const float* proj_w    = (const float*)d_in[8];
  const float* proj_b    = (const float*)d_in[9];
  const float* fw        = (const float*)d_in[10];
  const float* fb        = (const float*)d_in[11];
  const float* w1        = (const float*)d_in[12];
  const float* b1        = (const float*)d_in[13];
  const float* w2        = (const float*)d_in[14];
  const float* b2        = (const float*)d_in[15];

  char* ws = (char*)d_ws;
  unsigned short* q    = (unsigned short*)(ws);                    // BL*32 fp16 = 2MB
  unsigned short* k    = (unsigned short*)(ws + 2097152);          // 2MB
  unsigned short* v    = (unsigned short*)(ws + 4194304);          // 2MB
  float*          y2   = (float*)(ws + 6291456);                   // BL*64 f32 = 8MB
  unsigned short* wctT = (unsigned short*)(ws + 14680064);         // 64*800 fp16
  float*          bc   = (float*)(ws + 14782464);                  // 64 f32
  unsigned short* w1h  = (unsigned short*)(ws + 14782720);         // 8192 fp16
  unsigned short* w2h  = (unsigned short*)(ws + 14799104);         // 8192 fp16
  float* out = (float*)d_out;

  k_combine<<<203, 256, 0, stream>>>(proj_w, proj_b, fw, fb, w1, w2, wctT, bc, w1h, w2h);
  k_ln_qkv<<<dim3(BL/128, 3), 128, 0, stream>>>(x, qkv_w, qkv_b, n1w, n1b, q, k, v);
  k_attn<<<dim3(WW/TW, HH/TH, 2), 256, 0, stream>>>(q, k, v, rel_table, wctT, bc, y2);
  k_mlp<<<BL/64, 256, 0, stream>>>(y2, n2w, n2b, w1h, b1, w2h, b2, out);
}

// Round 17
// 88.045 us; speedup vs baseline: 1.1207x; 1.0087x over previous
//
#include <hip/hip_runtime.h>
#include <cstdint>
#include <cstddef>

#define HH 128
#define WW 128
#define LL 16384   // HH*WW
#define BL 32768   // B*LL

typedef float  f32x4  __attribute__((ext_vector_type(4)));
typedef __fp16 h2     __attribute__((ext_vector_type(2)));
typedef __fp16 h8     __attribute__((ext_vector_type(8)));

union U32H { unsigned u; h2 h; };

static __device__ __forceinline__ float fdot2(h2 a, h2 b, float c) {
  return __builtin_amdgcn_fdot2(a, b, c, false);
}
static __device__ __forceinline__ unsigned pkh2(float a, float b) {
  h2 h = __builtin_amdgcn_cvt_pkrtz(a, b);
  U32H t; t.h = h; return t.u;
}
static __device__ __forceinline__ h2 bcasth(float a) {
  return __builtin_amdgcn_cvt_pkrtz(a, a);
}
static __device__ __forceinline__ unsigned short f2h(float x) {
  union { __fp16 h; unsigned short u; } c; c.h = (__fp16)x; return c.u;
}

#define LOADH8(dst, ptr) { \
  uint4 _a = *(const uint4*)(ptr); uint4 _b = *(const uint4*)((ptr)+8); U32H _t; \
  _t.u=_a.x; dst[0]=_t.h; _t.u=_a.y; dst[1]=_t.h; _t.u=_a.z; dst[2]=_t.h; _t.u=_a.w; dst[3]=_t.h; \
  _t.u=_b.x; dst[4]=_t.h; _t.u=_b.y; dst[5]=_t.h; _t.u=_b.z; dst[6]=_t.h; _t.u=_b.w; dst[7]=_t.h; }

// ---- k0: fold proj into fusion weight (fp16 B^T [64][800], kk = t*32+c); cast w1/w2 --
__global__ __launch_bounds__(256) void k_combine(
    const float* __restrict__ proj_w, const float* __restrict__ proj_b,
    const float* __restrict__ fw, const float* __restrict__ fb,
    const float* __restrict__ w1, const float* __restrict__ w2,
    unsigned short* __restrict__ wctT, float* __restrict__ bc,
    unsigned short* __restrict__ w1h, unsigned short* __restrict__ w2h)
{
  if (blockIdx.x == 200) {
    int o = threadIdx.x;
    if (o < 64) {
      float acc = proj_b[o];
      for (int m = 0; m < 64; ++m) acc = fmaf(proj_w[o*64+m], fb[m], acc);
      bc[o] = acc;
    }
    return;
  }
  if (blockIdx.x == 201) {
    for (int i = threadIdx.x; i < 8192; i += 256) w1h[i] = f2h(w1[i]);
    return;
  }
  if (blockIdx.x == 202) {
    for (int i = threadIdx.x; i < 8192; i += 256) w2h[i] = f2h(w2[i]);
    return;
  }
  int gid = blockIdx.x * 256 + threadIdx.x;   // 0..51199 = o*800 + kk
  int o  = gid / 800;
  int kk = gid - o * 800;
  int c  = kk & 31;        // de-interleaved channel (nh*16+d)
  int t  = kk >> 5;        // window position 0..24
  int in = c * 25 + t;     // fusion weight flat index
  float acc = 0.f;
  for (int m = 0; m < 64; ++m) acc = fmaf(proj_w[o*64+m], fw[m*800+in], acc);
  wctT[gid] = f2h(acc);
}

// ---- k1: LayerNorm + QKV, fp16 out, de-interleaved (c' = nh*16 + d); 3-way split ----
__global__ __launch_bounds__(128) void k_ln_qkv(
    const float* __restrict__ x, const float* __restrict__ qkv_w,
    const float* __restrict__ qkv_b, const float* __restrict__ n1w,
    const float* __restrict__ n1b, unsigned short* __restrict__ qo,
    unsigned short* __restrict__ ko, unsigned short* __restrict__ vo)
{
  __shared__ float sW[32*32];
  __shared__ float sB[32];
  __shared__ float sNw[32], sNb[32];
  int p = blockIdx.y;                         // 0=q 1=k 2=v
  for (int i = threadIdx.x; i < 32*32; i += 128) sW[i] = qkv_w[p*1024 + i];
  if (threadIdx.x < 32) {
    sB[threadIdx.x]  = qkv_b[p*32 + threadIdx.x];
    sNw[threadIdx.x] = n1w[threadIdx.x];
    sNb[threadIdx.x] = n1b[threadIdx.x];
  }
  __syncthreads();
  int gid = blockIdx.x * 128 + threadIdx.x;   // 0..BL-1
  int b = gid >> 14, l = gid & (LL - 1);
  const float* xp = x + (size_t)b * 32 * LL + l;
  float xv[32];
  float mean = 0.f;
  #pragma unroll
  for (int c = 0; c < 32; ++c) { xv[c] = xp[(size_t)c * LL]; mean += xv[c]; }
  mean *= 0.03125f;
  float var = 0.f;
  #pragma unroll
  for (int c = 0; c < 32; ++c) { float d = xv[c] - mean; var = fmaf(d, d, var); }
  float rs = rsqrtf(var * 0.03125f + 1e-5f);
  #pragma unroll
  for (int c = 0; c < 32; ++c) xv[c] = (xv[c] - mean) * rs * sNw[c] + sNb[c];
  float ao[32];
  #pragma unroll
  for (int o = 0; o < 32; ++o) {
    const float* wr = &sW[o * 32];
    float acc = sB[o];
    #pragma unroll
    for (int c = 0; c < 32; ++c) acc = fmaf(xv[c], wr[c], acc);
    ao[(o & 1) * 16 + (o >> 1)] = acc;        // de-interleave heads
  }
  unsigned short* op = (p == 0 ? qo : p == 1 ? ko : vo) + (size_t)gid * 32;
  #pragma unroll
  for (int e = 0; e < 4; ++e) {
    uint4 pk4;
    pk4.x = pkh2(ao[e*8+0], ao[e*8+1]);
    pk4.y = pkh2(ao[e*8+2], ao[e*8+3]);
    pk4.z = pkh2(ao[e*8+4], ao[e*8+5]);
    pk4.w = pkh2(ao[e*8+6], ao[e*8+7]);
    *(uint4*)(op + e*8) = pk4;
  }
}

// ---- k2: TH=2 tile (16 locs), parity-scheduled fused L+S rows, Q from L2 ------------
#define TH 2
#define TW 8
#define NPOS 72   // 6x12 halo
#define KVSTR 24  // per-head fp16 row stride in ushorts (48B)
#define OSTRU 524 // sO row stride (ushorts): 512 kk + 12 pad

// CLS: class parity of the slot's locations. SLOW: full mask logic (boundary blocks).
template<int CLS, bool SLOW>
static __device__ __forceinline__ void attn_ls(
    int tqL, int tqS, bool wL, bool wS, int nh,
    int h0, int w0, int ly, int lx, int b,
    const unsigned short* __restrict__ qi,
    int posb, int sOrow, int klbase,
    const unsigned short* __restrict__ sK,
    const unsigned short* __restrict__ sV, unsigned short* __restrict__ sO,
    const float* __restrict__ sRT, const float* __restrict__ sPar)
{
  const int nhb = nh * 72;
  int iqL = tqL / 5, jqL = tqL - iqL * 5;
  int iqS = tqS / 5, jqS = tqS - iqS * 5;
  int hqL = h0 + ly + iqL - 2, wqL = w0 + lx + jqL - 2;
  int hqS = h0 + ly + iqS - 2, wqS = w0 + lx + jqS - 2;
  h2 qL[8], qS[8];
  float parqL = 0.f, parqS = 0.f;
  if (SLOW) {
    bool vL = ((unsigned)hqL < HH) && ((unsigned)wqL < WW);
    bool vS = ((unsigned)hqS < HH) && ((unsigned)wqS < WW);
    parqL = (vL && (((hqL + wqL) & 1) == 1)) ? 1.f : 0.f;
    parqS = (vS && (((hqS + wqS) & 1) == 1)) ? 1.f : 0.f;
    if (vL) {
      LOADH8(qL, qi + ((size_t)((b<<14)+(hqL<<7)+wqL))*32 + nh*16);
    } else {
      for (int u = 0; u < 8; ++u) qL[u] = (h2)(__fp16)0.f;
    }
    if (vS) {
      LOADH8(qS, qi + ((size_t)((b<<14)+(hqS<<7)+wqS))*32 + nh*16);
    } else {
      for (int u = 0; u < 8; ++u) qS[u] = (h2)(__fp16)0.f;
    }
  } else {
    LOADH8(qL, qi + ((size_t)((b<<14)+(hqL<<7)+wqL))*32 + nh*16);
    LOADH8(qS, qi + ((size_t)((b<<14)+(hqS<<7)+wqS))*32 + nh*16);
  }
  const int bbL = (iqL * 9 + jqL) * 2 + 80 + nh;
  const int bbS = (iqS * 9 + jqS) * 2 + 80 + nh;
  float sumL = 0.f, sumS = 0.f;
  h2 ooL[8], ooS[8];
  #pragma unroll
  for (int e = 0; e < 8; ++e) { ooL[e] = (h2)(__fp16)0.f; ooS[e] = (h2)(__fp16)0.f; }
  #pragma unroll 1
  for (int ik = 0; ik < 5; ++ik) {
    int pkrow = posb + ik * 12;
    int bL = bbL - ik * 18, bS = bbS - ik * 18;
    auto body = [&](int jk, bool doS) {
      int pk = pkrow + jk;
      h2 kh[8]; LOADH8(kh, &sK[(nhb + pk) * KVSTR]);
      h2 vh[8]; LOADH8(vh, &sV[(nhb + pk) * KVSTR]);
      float mk = 0.f;
      if (SLOW) { float park = sPar[pk]; mk = (park == 1.f) ? 0.f : -100.f; }
      {
        float a = 0.f;
        #pragma unroll
        for (int u = 0; u < 8; ++u) a = fdot2(qL[u], kh[u], a);
        float e = SLOW ? __expf(fmaf(parqL, mk, fmaf(a, 0.25f, sRT[bL - 2*jk])))
                       : __expf(fmaf(a, 0.25f, sRT[bL - 2*jk]));
        sumL += e;
        h2 eh = bcasth(e);
        #pragma unroll
        for (int u = 0; u < 8; ++u) ooL[u] = eh * vh[u] + ooL[u];
      }
      if (doS) {
        float a = 0.f;
        #pragma unroll
        for (int u = 0; u < 8; ++u) a = fdot2(qS[u], kh[u], a);
        float e = SLOW ? __expf(fmaf(parqS, mk, fmaf(a, 0.25f, sRT[bS - 2*jk])))
                       : __expf(fmaf(a, 0.25f, sRT[bS - 2*jk]));
        sumS += e;
        h2 eh = bcasth(e);
        #pragma unroll
        for (int u = 0; u < 8; ++u) ooS[u] = eh * vh[u] + ooS[u];
      }
    };
    if (SLOW) {
      body(0,true); body(1,true); body(2,true); body(3,true); body(4,true);
    } else if (CLS == 0) {      // S active when (ik+jk) odd
      if ((ik & 1) == 0) { body(0,false); body(1,true);  body(2,false); body(3,true);  body(4,false); }
      else               { body(0,true);  body(1,false); body(2,true);  body(3,false); body(4,true); }
    } else {                    // S active when (ik+jk) even
      if ((ik & 1) == 0) { body(0,true);  body(1,false); body(2,true);  body(3,false); body(4,true); }
      else               { body(0,false); body(1,true);  body(2,false); body(3,true);  body(4,false); }
    }
  }
  if (wL) {
    h2 ih = bcasth(1.f / sumL);
    int kl = (tqL - klbase) * 32 + nh * 16;
    union { h2 h[8]; uint4 u4[2]; } R;
    #pragma unroll
    for (int u = 0; u < 8; ++u) R.h[u] = ooL[u] * ih;
    *(uint4*)&sO[sOrow * OSTRU + kl] = R.u4[0];
    *(uint4*)&sO[sOrow * OSTRU + kl + 8] = R.u4[1];
  }
  if (wS) {
    h2 ih = bcasth(1.f / sumS);
    int kl = (tqS - klbase) * 32 + nh * 16;
    union { h2 h[8]; uint4 u4[2]; } R;
    #pragma unroll
    for (int u = 0; u < 8; ++u) R.h[u] = ooS[u] * ih;
    *(uint4*)&sO[sOrow * OSTRU + kl] = R.u4[0];
    *(uint4*)&sO[sOrow * OSTRU + kl + 8] = R.u4[1];
  }
}

__global__ __launch_bounds__(256, 5) void k_attn(
    const unsigned short* __restrict__ qi, const unsigned short* __restrict__ ki,
    const unsigned short* __restrict__ vi, const float* __restrict__ rel_table,
    const unsigned short* __restrict__ wctT, const float* __restrict__ bc,
    float* __restrict__ y2)
{
  __shared__ __align__(16) unsigned short sK[144*KVSTR]; // 6912 B
  __shared__ __align__(16) unsigned short sV[144*KVSTR]; // 6912 B
  __shared__ __align__(16) unsigned short sO[16*OSTRU];  // 16768 B
  __shared__ float sRT[162];
  __shared__ float sPar[NPOS];
  // total ~31.5 KB -> 5 blocks/CU

  int tid = threadIdx.x;
  int lane = tid & 63, wv = tid >> 6;
  int b  = blockIdx.z;
  int h0 = blockIdx.y * TH, w0 = blockIdx.x * TW;
  bool fastb = (blockIdx.y >= 1) && (blockIdx.y <= 62) && (blockIdx.x >= 1) && (blockIdx.x <= 14);

  for (int i = tid; i < 162; i += 256) sRT[i] = rel_table[i];
  if (tid < NPOS) {
    int ph = tid / 12, pw = tid - ph * 12;
    int h2v = h0 + ph - 2, w2v = w0 + pw - 2;
    bool valid = ((unsigned)h2v < HH) && ((unsigned)w2v < WW);
    sPar[tid] = (valid && (((h2v + w2v) & 1) == 1)) ? 1.f : 0.f;
  }
  // halo staging: K,V: 2 arrays x 72 pos x 2 nh x 2 half-chunks(16B) = 576 units
  for (int idx = tid; idx < 576; idx += 256) {
    int arr = idx / 288;                  // 0=K, 1=V
    int rem = idx - arr * 288;
    int pos = rem >> 2, q4 = rem & 3;
    int nh = q4 >> 1, half = q4 & 1;
    int ph = pos / 12, pw = pos - ph * 12;
    int h2v = h0 + ph - 2, w2v = w0 + pw - 2;
    uint4 val = make_uint4(0u, 0u, 0u, 0u);
    if (((unsigned)h2v < HH) && ((unsigned)w2v < WW)) {
      const unsigned short* src = (arr == 0 ? ki : vi)
                       + ((size_t)((b << 14) + (h2v << 7) + w2v)) * 32 + nh * 16 + half * 8;
      val = *(const uint4*)src;
    }
    unsigned short* dp = (arr == 0 ? sK : sV) + (nh * 72 + pos) * KVSTR + half * 8;
    *(uint4*)dp = val;
  }
  __syncthreads();

  f32x4 acc = {0.f, 0.f, 0.f, 0.f};
  int ocol = wv * 16 + (lane & 15);

  // slot geometry: 8-lane groups; cls = wave parity class; r8 = row-slot
  int cls = wv & 1;                         // wave-uniform
  int nh  = wv >> 1;
  int l8  = lane & 7;
  int r8  = lane >> 3;                      // 0..7
  int ly  = l8 >> 2;
  int lx  = 2 * (l8 & 3) + ((cls + ly) & 1);
  int posb  = ly * 12 + lx;
  int sOrow = cls * 8 + l8;

  // ---- phase 0: rows tq 0..15 (L rows: class-long; S rows: class-short)
  if (fastb) {
    if (cls == 0) attn_ls<0,false>(2*r8,   2*r8+1, true, true, nh, h0,w0,ly,lx,b,qi, posb, sOrow, 0, sK, sV, sO, sRT, sPar);
    else          attn_ls<1,false>(2*r8+1, 2*r8,   true, true, nh, h0,w0,ly,lx,b,qi, posb, sOrow, 0, sK, sV, sO, sRT, sPar);
  } else {
    int tl = (cls == 0) ? 2*r8 : 2*r8+1;
    int ts = (cls == 0) ? 2*r8+1 : 2*r8;
    attn_ls<0,true>(tl, ts, true, true, nh, h0,w0,ly,lx,b,qi, posb, sOrow, 0, sK, sV, sO, sRT, sPar);
  }
  __syncthreads();
  {
    const unsigned short* bcol = wctT + (size_t)ocol * 800 + (lane >> 4) * 8;
    for (int kt = 0; kt < 16; ++kt) {
      h8 bfrag = *(const h8*)(bcol + kt * 32);
      h8 afrag = *(const h8*)&sO[(lane & 15)*OSTRU + kt*32 + (lane >> 4)*8];
      acc = __builtin_amdgcn_mfma_f32_16x16x32_f16(afrag, bfrag, acc, 0, 0, 0);
    }
  }
  __syncthreads();

  // ---- phase 1: rows tq 16..24
  {
    int tqL, tqS; bool wL, wS;
    if (cls == 0) {
      tqL = (r8 < 5) ? 16 + 2*r8 : 16; wL = (r8 < 5);
      tqS = (r8 < 4) ? 17 + 2*r8 : 17; wS = (r8 < 4);
    } else {
      tqL = (r8 < 4) ? 17 + 2*r8 : 17; wL = (r8 < 4);
      tqS = (r8 < 5) ? 16 + 2*r8 : 16; wS = (r8 < 5);
    }
    if (fastb) {
      if (cls == 0) attn_ls<0,false>(tqL, tqS, wL, wS, nh, h0,w0,ly,lx,b,qi, posb, sOrow, 16, sK, sV, sO, sRT, sPar);
      else          attn_ls<1,false>(tqL, tqS, wL, wS, nh, h0,w0,ly,lx,b,qi, posb, sOrow, 16, sK, sV, sO, sRT, sPar);
    } else {
      attn_ls<0,true>(tqL, tqS, wL, wS, nh, h0,w0,ly,lx,b,qi, posb, sOrow, 16, sK, sV, sO, sRT, sPar);
    }
  }
  __syncthreads();
  {
    const unsigned short* bcol = wctT + (size_t)ocol * 800 + 512 + (lane >> 4) * 8;
    for (int kt = 0; kt < 9; ++kt) {
      h8 bfrag = *(const h8*)(bcol + kt * 32);
      h8 afrag = *(const h8*)&sO[(lane & 15)*OSTRU + kt*32 + (lane >> 4)*8];
      acc = __builtin_amdgcn_mfma_f32_16x16x32_f16(afrag, bfrag, acc, 0, 0, 0);
    }
  }
  __syncthreads();

  // epilogue: class-major row -> (ly,lx) remap
  float bco = bc[ocol];
  #pragma unroll
  for (int r2 = 0; r2 < 4; ++r2) {
    int r = (lane >> 4) * 4 + r2;           // 0..15
    int cls2 = r >> 3, i8 = r & 7;
    int ly2 = i8 >> 2, lx2 = 2 * (i8 & 3) + ((cls2 + ly2) & 1);
    int gid = (b << 14) + ((h0 + ly2) << 7) + (w0 + lx2);
    y2[(size_t)gid * 64 + ocol] = acc[r2] + bco;
  }
}

// ---- k3: LN + MLP via MFMA f16 (GELU exact), M0=32 tiles (1024 blocks) --------------
__global__ __launch_bounds__(256) void k_mlp(
    const float* __restrict__ y2, const float* __restrict__ n2w,
    const float* __restrict__ n2b, const unsigned short* __restrict__ w1h,
    const float* __restrict__ b1, const unsigned short* __restrict__ w2h,
    const float* __restrict__ b2, float* __restrict__ out)
{
  __shared__ __align__(16) unsigned short sA[32*72];   // 4608 B
  __shared__ __align__(16) unsigned short sH[32*136];  // 8704 B
  int tid = threadIdx.x;
  int lane = tid & 63, wv = tid >> 6;
  int m0 = blockIdx.x * 32;
  // ---- LN: 8 threads per row (32 rows)
  {
    int r = tid >> 3, qd = tid & 7;
    const float* yp = y2 + (size_t)(m0 + r) * 64 + qd * 8;
    float xv[8];
    float s = 0.f;
    #pragma unroll
    for (int e = 0; e < 2; ++e) {
      float4 t4 = *(const float4*)(yp + e*4);
      xv[4*e] = t4.x; xv[4*e+1] = t4.y; xv[4*e+2] = t4.z; xv[4*e+3] = t4.w;
      s += t4.x + t4.y + t4.z + t4.w;
    }
    s += __shfl_xor(s, 1);
    s += __shfl_xor(s, 2);
    s += __shfl_xor(s, 4);
    float mean = s * (1.f/64.f);
    float v = 0.f;
    #pragma unroll
    for (int e = 0; e < 8; ++e) { float d = xv[e] - mean; v = fmaf(d, d, v); }
    v += __shfl_xor(v, 1);
    v += __shfl_xor(v, 2);
    v += __shfl_xor(v, 4);
    float rs = rsqrtf(v * (1.f/64.f) + 1e-5f);
    #pragma unroll
    for (int u = 0; u < 4; ++u) {
      int c0 = qd*8 + 2*u;
      float h0v = (xv[2*u]   - mean) * rs * n2w[c0]   + n2b[c0];
      float h1v = (xv[2*u+1] - mean) * rs * n2w[c0+1] + n2b[c0+1];
      *(unsigned*)&sA[r*72 + c0] = pkh2(h0v, h1v);
    }
  }
  __syncthreads();
  // ---- GEMM1: [32x64] x W1^T -> [32x128], n-slice 32 per wave
  f32x4 acc1[2][2];
  #pragma unroll
  for (int mt = 0; mt < 2; ++mt)
    #pragma unroll
    for (int nt = 0; nt < 2; ++nt) acc1[mt][nt] = (f32x4){0.f,0.f,0.f,0.f};
  #pragma unroll
  for (int kt = 0; kt < 2; ++kt) {
    #pragma unroll
    for (int nt = 0; nt < 2; ++nt) {
      int ncol = wv*32 + nt*16 + (lane & 15);
      h8 bfrag = *(const h8*)(w1h + ncol*64 + kt*32 + (lane >> 4)*8);
      #pragma unroll
      for (int mt = 0; mt < 2; ++mt) {
        h8 afrag = *(const h8*)&sA[(mt*16 + (lane & 15))*72 + kt*32 + (lane >> 4)*8];
        acc1[mt][nt] = __builtin_amdgcn_mfma_f32_16x16x32_f16(afrag, bfrag, acc1[mt][nt], 0, 0, 0);
      }
    }
  }
  // ---- bias + exact GELU -> sH (fp16)
  #pragma unroll
  for (int nt = 0; nt < 2; ++nt) {
    int ncol = wv*32 + nt*16 + (lane & 15);
    float b1v = b1[ncol];
    #pragma unroll
    for (int mt = 0; mt < 2; ++mt) {
      #pragma unroll
      for (int r2 = 0; r2 < 4; ++r2) {
        int mrow = mt*16 + (lane >> 4)*4 + r2;
        float h = acc1[mt][nt][r2] + b1v;
        float g = 0.5f * h * (1.f + erff(h * 0.70710678118f));
        sH[mrow*136 + ncol] = f2h(g);
      }
    }
  }
  __syncthreads();
  // ---- GEMM2: [32x128] x W2^T -> [32x64], n-slice 16 per wave
  f32x4 acc2[2];
  #pragma unroll
  for (int mt = 0; mt < 2; ++mt) acc2[mt] = (f32x4){0.f,0.f,0.f,0.f};
  int ocol = wv*16 + (lane & 15);
  #pragma unroll
  for (int kt = 0; kt < 4; ++kt) {
    h8 bfrag = *(const h8*)(w2h + ocol*128 + kt*32 + (lane >> 4)*8);
    #pragma unroll
    for (int mt = 0; mt < 2; ++mt) {
      h8 afrag = *(const h8*)&sH[(mt*16 + (lane & 15))*136 + kt*32 + (lane >> 4)*8];
      acc2[mt] = __builtin_amdgcn_mfma_f32_16x16x32_f16(afrag, bfrag, acc2[mt], 0, 0, 0);
    }
  }
  // ---- residual + bias + transpose store
  float b2v = b2[ocol];
  int bb = m0 >> 14;
  #pragma unroll
  for (int mt = 0; mt < 2; ++mt) {
    int mrow = mt*16 + (lane >> 4)*4;
    int l = m0 + mrow;
    const float* yp = y2 + (size_t)l * 64 + ocol;
    float4 o4;
    o4.x = yp[0]   + acc2[mt][0] + b2v;
    o4.y = yp[64]  + acc2[mt][1] + b2v;
    o4.z = yp[128] + acc2[mt][2] + b2v;
    o4.w = yp[192] + acc2[mt][3] + b2v;
    *(float4*)&out[(size_t)bb * 64 * LL + (size_t)ocol * LL + (l - (bb << 14))] = o4;
  }
}

extern "C" void kernel_launch(void* const* d_in, const int* in_sizes, int n_in,
                              void* d_out, int out_size, void* d_ws, size_t ws_size,
                              hipStream_t stream) {
  const float* x         = (const float*)d_in[0];
  const float* qkv_w     = (const float*)d_in[1];
  const float* qkv_b     = (const float*)d_in[2];
  const float* rel_table = (const float*)d_in[3];
  const float* n1w       = (const float*)d_in[4];
  const float* n1b       = (const float*)d_in[5];
  const float* n2w       = (const float*)d_in[6];
  const float* n2b       = (const float*)d_in[7];
  const float* proj_w    = (const float*)d_in[8];
  const float* proj_b    = (const float*)d_in[9];
  const float* fw        = (const float*)d_in[10];
  const float* fb        = (const float*)d_in[11];
  const float* w1        = (const float*)d_in[12];
  const float* b1        = (const float*)d_in[13];
  const float* w2        = (const float*)d_in[14];
  const float* b2        = (const float*)d_in[15];

  char* ws = (char*)d_ws;
  unsigned short* q    = (unsigned short*)(ws);                    // BL*32 fp16 = 2MB
  unsigned short* k    = (unsigned short*)(ws + 2097152);          // 2MB
  unsigned short* v    = (unsigned short*)(ws + 4194304);          // 2MB
  float*          y2   = (float*)(ws + 6291456);                   // BL*64 f32 = 8MB
  unsigned short* wctT = (unsigned short*)(ws + 14680064);         // 64*800 fp16
  float*          bc   = (float*)(ws + 14782464);                  // 64 f32
  unsigned short* w1h  = (unsigned short*)(ws + 14782720);         // 8192 fp16
  unsigned short* w2h  = (unsigned short*)(ws + 14799104);         // 8192 fp16
  float* out = (float*)d_out;

  k_combine<<<203, 256, 0, stream>>>(proj_w, proj_b, fw, fb, w1, w2, wctT, bc, w1h, w2h);
  k_ln_qkv<<<dim3(BL/128, 3), 128, 0, stream>>>(x, qkv_w, qkv_b, n1w, n1b, q, k, v);
  k_attn<<<dim3(WW/TW, HH/TH, 2), 256, 0, stream>>>(q, k, v, rel_table, wctT, bc, y2);
  k_mlp<<<BL/32, 256, 0, stream>>>(y2, n2w, n2b, w1h, b1, w2h, b2, out);
}

// Round 18
// 86.186 us; speedup vs baseline: 1.1449x; 1.0216x over previous
//
#include <hip/hip_runtime.h>
#include <cstdint>
#include <cstddef>

#define HH 128
#define WW 128
#define LL 16384   // HH*WW
#define BL 32768   // B*LL

typedef float  f32x4  __attribute__((ext_vector_type(4)));
typedef __fp16 h2     __attribute__((ext_vector_type(2)));
typedef __fp16 h8     __attribute__((ext_vector_type(8)));

union U32H { unsigned u; h2 h; };

static __device__ __forceinline__ float fdot2(h2 a, h2 b, float c) {
  return __builtin_amdgcn_fdot2(a, b, c, false);
}
static __device__ __forceinline__ unsigned pkh2(float a, float b) {
  h2 h = __builtin_amdgcn_cvt_pkrtz(a, b);
  U32H t; t.h = h; return t.u;
}
static __device__ __forceinline__ h2 bcasth(float a) {
  return __builtin_amdgcn_cvt_pkrtz(a, a);
}
static __device__ __forceinline__ unsigned short f2h(float x) {
  union { __fp16 h; unsigned short u; } c; c.h = (__fp16)x; return c.u;
}

#define LOADH8(dst, ptr) { \
  uint4 _a = *(const uint4*)(ptr); uint4 _b = *(const uint4*)((ptr)+8); U32H _t; \
  _t.u=_a.x; dst[0]=_t.h; _t.u=_a.y; dst[1]=_t.h; _t.u=_a.z; dst[2]=_t.h; _t.u=_a.w; dst[3]=_t.h; \
  _t.u=_b.x; dst[4]=_t.h; _t.u=_b.y; dst[5]=_t.h; _t.u=_b.z; dst[6]=_t.h; _t.u=_b.w; dst[7]=_t.h; }

// ---- k0: fold proj into fusion weight (fp16 B^T [64][800], kk = t*32+c); cast w1/w2 --
__global__ __launch_bounds__(256) void k_combine(
    const float* __restrict__ proj_w, const float* __restrict__ proj_b,
    const float* __restrict__ fw, const float* __restrict__ fb,
    const float* __restrict__ w1, const float* __restrict__ w2,
    unsigned short* __restrict__ wctT, float* __restrict__ bc,
    unsigned short* __restrict__ w1h, unsigned short* __restrict__ w2h)
{
  if (blockIdx.x == 200) {
    int o = threadIdx.x;
    if (o < 64) {
      float acc = proj_b[o];
      for (int m = 0; m < 64; ++m) acc = fmaf(proj_w[o*64+m], fb[m], acc);
      bc[o] = acc;
    }
    return;
  }
  if (blockIdx.x == 201) {
    for (int i = threadIdx.x; i < 8192; i += 256) w1h[i] = f2h(w1[i]);
    return;
  }
  if (blockIdx.x == 202) {
    for (int i = threadIdx.x; i < 8192; i += 256) w2h[i] = f2h(w2[i]);
    return;
  }
  int gid = blockIdx.x * 256 + threadIdx.x;   // 0..51199 = o*800 + kk
  int o  = gid / 800;
  int kk = gid - o * 800;
  int c  = kk & 31;        // de-interleaved channel (nh*16+d)
  int t  = kk >> 5;        // window position 0..24
  int in = c * 25 + t;     // fusion weight flat index
  float acc = 0.f;
  for (int m = 0; m < 64; ++m) acc = fmaf(proj_w[o*64+m], fw[m*800+in], acc);
  wctT[gid] = f2h(acc);
}

// ---- k1: LayerNorm + QKV, fp16 out, de-interleaved (c' = nh*16 + d); 3-way split ----
__global__ __launch_bounds__(128) void k_ln_qkv(
    const float* __restrict__ x, const float* __restrict__ qkv_w,
    const float* __restrict__ qkv_b, const float* __restrict__ n1w,
    const float* __restrict__ n1b, unsigned short* __restrict__ qo,
    unsigned short* __restrict__ ko, unsigned short* __restrict__ vo)
{
  __shared__ float sW[32*32];
  __shared__ float sB[32];
  __shared__ float sNw[32], sNb[32];
  int p = blockIdx.y;                         // 0=q 1=k 2=v
  for (int i = threadIdx.x; i < 32*32; i += 128) sW[i] = qkv_w[p*1024 + i];
  if (threadIdx.x < 32) {
    sB[threadIdx.x]  = qkv_b[p*32 + threadIdx.x];
    sNw[threadIdx.x] = n1w[threadIdx.x];
    sNb[threadIdx.x] = n1b[threadIdx.x];
  }
  __syncthreads();
  int gid = blockIdx.x * 128 + threadIdx.x;   // 0..BL-1
  int b = gid >> 14, l = gid & (LL - 1);
  const float* xp = x + (size_t)b * 32 * LL + l;
  float xv[32];
  float mean = 0.f;
  #pragma unroll
  for (int c = 0; c < 32; ++c) { xv[c] = xp[(size_t)c * LL]; mean += xv[c]; }
  mean *= 0.03125f;
  float var = 0.f;
  #pragma unroll
  for (int c = 0; c < 32; ++c) { float d = xv[c] - mean; var = fmaf(d, d, var); }
  float rs = rsqrtf(var * 0.03125f + 1e-5f);
  #pragma unroll
  for (int c = 0; c < 32; ++c) xv[c] = (xv[c] - mean) * rs * sNw[c] + sNb[c];
  float ao[32];
  #pragma unroll
  for (int o = 0; o < 32; ++o) {
    const float* wr = &sW[o * 32];
    float acc = sB[o];
    #pragma unroll
    for (int c = 0; c < 32; ++c) acc = fmaf(xv[c], wr[c], acc);
    ao[(o & 1) * 16 + (o >> 1)] = acc;        // de-interleave heads
  }
  unsigned short* op = (p == 0 ? qo : p == 1 ? ko : vo) + (size_t)gid * 32;
  #pragma unroll
  for (int e = 0; e < 4; ++e) {
    uint4 pk4;
    pk4.x = pkh2(ao[e*8+0], ao[e*8+1]);
    pk4.y = pkh2(ao[e*8+2], ao[e*8+3]);
    pk4.z = pkh2(ao[e*8+4], ao[e*8+5]);
    pk4.w = pkh2(ao[e*8+6], ao[e*8+7]);
    *(uint4*)(op + e*8) = pk4;
  }
}

// ---- k2: TH=2 tile (16 locs), parity-scheduled fused L+S rows, Q from L2 ------------
#define TH 2
#define TW 8
#define NPOS 72   // 6x12 halo
#define KVSTR 24  // per-head fp16 row stride in ushorts (48B)
#define OSTRU 524 // sO row stride (ushorts): 512 kk + 12 pad

// CLS: class parity of the slot's locations. SLOW: full mask logic (boundary blocks).
template<int CLS, bool SLOW>
static __device__ __forceinline__ void attn_ls(
    int tqL, int tqS, bool wL, bool wS, int nh,
    int h0, int w0, int ly, int lx, int b,
    const unsigned short* __restrict__ qi,
    int posb, int sOrow, int klbase,
    const unsigned short* __restrict__ sK,
    const unsigned short* __restrict__ sV, unsigned short* __restrict__ sO,
    const float* __restrict__ sRT, const float* __restrict__ sPar)
{
  const int nhb = nh * 72;
  int iqL = tqL / 5, jqL = tqL - iqL * 5;
  int iqS = tqS / 5, jqS = tqS - iqS * 5;
  int hqL = h0 + ly + iqL - 2, wqL = w0 + lx + jqL - 2;
  int hqS = h0 + ly + iqS - 2, wqS = w0 + lx + jqS - 2;
  h2 qL[8], qS[8];
  float parqL = 0.f, parqS = 0.f;
  if (SLOW) {
    bool vL = ((unsigned)hqL < HH) && ((unsigned)wqL < WW);
    bool vS = ((unsigned)hqS < HH) && ((unsigned)wqS < WW);
    parqL = (vL && (((hqL + wqL) & 1) == 1)) ? 1.f : 0.f;
    parqS = (vS && (((hqS + wqS) & 1) == 1)) ? 1.f : 0.f;
    if (vL) {
      LOADH8(qL, qi + ((size_t)((b<<14)+(hqL<<7)+wqL))*32 + nh*16);
    } else {
      for (int u = 0; u < 8; ++u) qL[u] = (h2)(__fp16)0.f;
    }
    if (vS) {
      LOADH8(qS, qi + ((size_t)((b<<14)+(hqS<<7)+wqS))*32 + nh*16);
    } else {
      for (int u = 0; u < 8; ++u) qS[u] = (h2)(__fp16)0.f;
    }
  } else {
    LOADH8(qL, qi + ((size_t)((b<<14)+(hqL<<7)+wqL))*32 + nh*16);
    LOADH8(qS, qi + ((size_t)((b<<14)+(hqS<<7)+wqS))*32 + nh*16);
  }
  const int bbL = (iqL * 9 + jqL) * 2 + 80 + nh;
  const int bbS = (iqS * 9 + jqS) * 2 + 80 + nh;
  float sumL = 0.f, sumS = 0.f;
  h2 ooL[8], ooS[8];
  #pragma unroll
  for (int e = 0; e < 8; ++e) { ooL[e] = (h2)(__fp16)0.f; ooS[e] = (h2)(__fp16)0.f; }
  #pragma unroll 1
  for (int ik = 0; ik < 5; ++ik) {
    int pkrow = posb + ik * 12;
    int bL = bbL - ik * 18, bS = bbS - ik * 18;
    auto body = [&](int jk, bool doS) {
      int pk = pkrow + jk;
      h2 kh[8]; LOADH8(kh, &sK[(nhb + pk) * KVSTR]);
      h2 vh[8]; LOADH8(vh, &sV[(nhb + pk) * KVSTR]);
      float mk = 0.f;
      if (SLOW) { float park = sPar[pk]; mk = (park == 1.f) ? 0.f : -100.f; }
      {
        float a = 0.f;
        #pragma unroll
        for (int u = 0; u < 8; ++u) a = fdot2(qL[u], kh[u], a);
        float e = SLOW ? __expf(fmaf(parqL, mk, fmaf(a, 0.25f, sRT[bL - 2*jk])))
                       : __expf(fmaf(a, 0.25f, sRT[bL - 2*jk]));
        sumL += e;
        h2 eh = bcasth(e);
        #pragma unroll
        for (int u = 0; u < 8; ++u) ooL[u] = eh * vh[u] + ooL[u];
      }
      if (doS) {
        float a = 0.f;
        #pragma unroll
        for (int u = 0; u < 8; ++u) a = fdot2(qS[u], kh[u], a);
        float e = SLOW ? __expf(fmaf(parqS, mk, fmaf(a, 0.25f, sRT[bS - 2*jk])))
                       : __expf(fmaf(a, 0.25f, sRT[bS - 2*jk]));
        sumS += e;
        h2 eh = bcasth(e);
        #pragma unroll
        for (int u = 0; u < 8; ++u) ooS[u] = eh * vh[u] + ooS[u];
      }
    };
    if (SLOW) {
      body(0,true); body(1,true); body(2,true); body(3,true); body(4,true);
    } else if (CLS == 0) {      // S active when (ik+jk) odd
      if ((ik & 1) == 0) { body(0,false); body(1,true);  body(2,false); body(3,true);  body(4,false); }
      else               { body(0,true);  body(1,false); body(2,true);  body(3,false); body(4,true); }
    } else {                    // S active when (ik+jk) even
      if ((ik & 1) == 0) { body(0,true);  body(1,false); body(2,true);  body(3,false); body(4,true); }
      else               { body(0,false); body(1,true);  body(2,false); body(3,true);  body(4,false); }
    }
  }
  if (wL) {
    h2 ih = bcasth(1.f / sumL);
    int kl = (tqL - klbase) * 32 + nh * 16;
    union { h2 h[8]; uint4 u4[2]; } R;
    #pragma unroll
    for (int u = 0; u < 8; ++u) R.h[u] = ooL[u] * ih;
    *(uint4*)&sO[sOrow * OSTRU + kl] = R.u4[0];
    *(uint4*)&sO[sOrow * OSTRU + kl + 8] = R.u4[1];
  }
  if (wS) {
    h2 ih = bcasth(1.f / sumS);
    int kl = (tqS - klbase) * 32 + nh * 16;
    union { h2 h[8]; uint4 u4[2]; } R;
    #pragma unroll
    for (int u = 0; u < 8; ++u) R.h[u] = ooS[u] * ih;
    *(uint4*)&sO[sOrow * OSTRU + kl] = R.u4[0];
    *(uint4*)&sO[sOrow * OSTRU + kl + 8] = R.u4[1];
  }
}

__global__ __launch_bounds__(256, 4) void k_attn(
    const unsigned short* __restrict__ qi, const unsigned short* __restrict__ ki,
    const unsigned short* __restrict__ vi, const float* __restrict__ rel_table,
    const unsigned short* __restrict__ wctT, const float* __restrict__ bc,
    float* __restrict__ y2)
{
  __shared__ __align__(16) unsigned short sK[144*KVSTR]; // 6912 B
  __shared__ __align__(16) unsigned short sV[144*KVSTR]; // 6912 B
  __shared__ __align__(16) unsigned short sO[16*OSTRU];  // 16768 B
  __shared__ float sRT[162];
  __shared__ float sPar[NPOS];
  // total ~31.5 KB -> 4 blocks/CU (VGPR-bound; LDS would allow 5)

  int tid = threadIdx.x;
  int lane = tid & 63, wv = tid >> 6;
  int b  = blockIdx.z;
  int h0 = blockIdx.y * TH, w0 = blockIdx.x * TW;
  bool fastb = (blockIdx.y >= 1) && (blockIdx.y <= 62) && (blockIdx.x >= 1) && (blockIdx.x <= 14);

  for (int i = tid; i < 162; i += 256) sRT[i] = rel_table[i];
  if (tid < NPOS) {
    int ph = tid / 12, pw = tid - ph * 12;
    int h2v = h0 + ph - 2, w2v = w0 + pw - 2;
    bool valid = ((unsigned)h2v < HH) && ((unsigned)w2v < WW);
    sPar[tid] = (valid && (((h2v + w2v) & 1) == 1)) ? 1.f : 0.f;
  }
  // halo staging: K,V: 2 arrays x 72 pos x 2 nh x 2 half-chunks(16B) = 576 units
  for (int idx = tid; idx < 576; idx += 256) {
    int arr = idx / 288;                  // 0=K, 1=V
    int rem = idx - arr * 288;
    int pos = rem >> 2, q4 = rem & 3;
    int nh = q4 >> 1, half = q4 & 1;
    int ph = pos / 12, pw = pos - ph * 12;
    int h2v = h0 + ph - 2, w2v = w0 + pw - 2;
    uint4 val = make_uint4(0u, 0u, 0u, 0u);
    if (((unsigned)h2v < HH) && ((unsigned)w2v < WW)) {
      const unsigned short* src = (arr == 0 ? ki : vi)
                       + ((size_t)((b << 14) + (h2v << 7) + w2v)) * 32 + nh * 16 + half * 8;
      val = *(const uint4*)src;
    }
    unsigned short* dp = (arr == 0 ? sK : sV) + (nh * 72 + pos) * KVSTR + half * 8;
    *(uint4*)dp = val;
  }
  __syncthreads();

  f32x4 acc = {0.f, 0.f, 0.f, 0.f};
  int ocol = wv * 16 + (lane & 15);

  // slot geometry: 8-lane groups; cls = wave parity class; r8 = row-slot
  int cls = wv & 1;                         // wave-uniform
  int nh  = wv >> 1;
  int l8  = lane & 7;
  int r8  = lane >> 3;                      // 0..7
  int ly  = l8 >> 2;
  int lx  = 2 * (l8 & 3) + ((cls + ly) & 1);
  int posb  = ly * 12 + lx;
  int sOrow = cls * 8 + l8;

  // ---- phase 0: rows tq 0..15 (L rows: class-long; S rows: class-short)
  if (fastb) {
    if (cls == 0) attn_ls<0,false>(2*r8,   2*r8+1, true, true, nh, h0,w0,ly,lx,b,qi, posb, sOrow, 0, sK, sV, sO, sRT, sPar);
    else          attn_ls<1,false>(2*r8+1, 2*r8,   true, true, nh, h0,w0,ly,lx,b,qi, posb, sOrow, 0, sK, sV, sO, sRT, sPar);
  } else {
    int tl = (cls == 0) ? 2*r8 : 2*r8+1;
    int ts = (cls == 0) ? 2*r8+1 : 2*r8;
    attn_ls<0,true>(tl, ts, true, true, nh, h0,w0,ly,lx,b,qi, posb, sOrow, 0, sK, sV, sO, sRT, sPar);
  }
  __syncthreads();
  {
    const unsigned short* bcol = wctT + (size_t)ocol * 800 + (lane >> 4) * 8;
    for (int kt = 0; kt < 16; ++kt) {
      h8 bfrag = *(const h8*)(bcol + kt * 32);
      h8 afrag = *(const h8*)&sO[(lane & 15)*OSTRU + kt*32 + (lane >> 4)*8];
      acc = __builtin_amdgcn_mfma_f32_16x16x32_f16(afrag, bfrag, acc, 0, 0, 0);
    }
  }
  __syncthreads();

  // ---- phase 1: rows tq 16..24
  {
    int tqL, tqS; bool wL, wS;
    if (cls == 0) {
      tqL = (r8 < 5) ? 16 + 2*r8 : 16; wL = (r8 < 5);
      tqS = (r8 < 4) ? 17 + 2*r8 : 17; wS = (r8 < 4);
    } else {
      tqL = (r8 < 4) ? 17 + 2*r8 : 17; wL = (r8 < 4);
      tqS = (r8 < 5) ? 16 + 2*r8 : 16; wS = (r8 < 5);
    }
    if (fastb) {
      if (cls == 0) attn_ls<0,false>(tqL, tqS, wL, wS, nh, h0,w0,ly,lx,b,qi, posb, sOrow, 16, sK, sV, sO, sRT, sPar);
      else          attn_ls<1,false>(tqL, tqS, wL, wS, nh, h0,w0,ly,lx,b,qi, posb, sOrow, 16, sK, sV, sO, sRT, sPar);
    } else {
      attn_ls<0,true>(tqL, tqS, wL, wS, nh, h0,w0,ly,lx,b,qi, posb, sOrow, 16, sK, sV, sO, sRT, sPar);
    }
  }
  __syncthreads();
  {
    const unsigned short* bcol = wctT + (size_t)ocol * 800 + 512 + (lane >> 4) * 8;
    for (int kt = 0; kt < 9; ++kt) {
      h8 bfrag = *(const h8*)(bcol + kt * 32);
      h8 afrag = *(const h8*)&sO[(lane & 15)*OSTRU + kt*32 + (lane >> 4)*8];
      acc = __builtin_amdgcn_mfma_f32_16x16x32_f16(afrag, bfrag, acc, 0, 0, 0);
    }
  }
  __syncthreads();

  // epilogue: class-major row -> (ly,lx) remap
  float bco = bc[ocol];
  #pragma unroll
  for (int r2 = 0; r2 < 4; ++r2) {
    int r = (lane >> 4) * 4 + r2;           // 0..15
    int cls2 = r >> 3, i8 = r & 7;
    int ly2 = i8 >> 2, lx2 = 2 * (i8 & 3) + ((cls2 + ly2) & 1);
    int gid = (b << 14) + ((h0 + ly2) << 7) + (w0 + lx2);
    y2[(size_t)gid * 64 + ocol] = acc[r2] + bco;
  }
}

// ---- k3: LN + MLP via MFMA f16 (GELU exact), M0=32 tiles (1024 blocks) --------------
__global__ __launch_bounds__(256) void k_mlp(
    const float* __restrict__ y2, const float* __restrict__ n2w,
    const float* __restrict__ n2b, const unsigned short* __restrict__ w1h,
    const float* __restrict__ b1, const unsigned short* __restrict__ w2h,
    const float* __restrict__ b2, float* __restrict__ out)
{
  __shared__ __align__(16) unsigned short sA[32*72];   // 4608 B
  __shared__ __align__(16) unsigned short sH[32*136];  // 8704 B
  int tid = threadIdx.x;
  int lane = tid & 63, wv = tid >> 6;
  int m0 = blockIdx.x * 32;
  // ---- LN: 8 threads per row (32 rows)
  {
    int r = tid >> 3, qd = tid & 7;
    const float* yp = y2 + (size_t)(m0 + r) * 64 + qd * 8;
    float xv[8];
    float s = 0.f;
    #pragma unroll
    for (int e = 0; e < 2; ++e) {
      float4 t4 = *(const float4*)(yp + e*4);
      xv[4*e] = t4.x; xv[4*e+1] = t4.y; xv[4*e+2] = t4.z; xv[4*e+3] = t4.w;
      s += t4.x + t4.y + t4.z + t4.w;
    }
    s += __shfl_xor(s, 1);
    s += __shfl_xor(s, 2);
    s += __shfl_xor(s, 4);
    float mean = s * (1.f/64.f);
    float v = 0.f;
    #pragma unroll
    for (int e = 0; e < 8; ++e) { float d = xv[e] - mean; v = fmaf(d, d, v); }
    v += __shfl_xor(v, 1);
    v += __shfl_xor(v, 2);
    v += __shfl_xor(v, 4);
    float rs = rsqrtf(v * (1.f/64.f) + 1e-5f);
    #pragma unroll
    for (int u = 0; u < 4; ++u) {
      int c0 = qd*8 + 2*u;
      float h0v = (xv[2*u]   - mean) * rs * n2w[c0]   + n2b[c0];
      float h1v = (xv[2*u+1] - mean) * rs * n2w[c0+1] + n2b[c0+1];
      *(unsigned*)&sA[r*72 + c0] = pkh2(h0v, h1v);
    }
  }
  __syncthreads();
  // ---- GEMM1: [32x64] x W1^T -> [32x128], n-slice 32 per wave
  f32x4 acc1[2][2];
  #pragma unroll
  for (int mt = 0; mt < 2; ++mt)
    #pragma unroll
    for (int nt = 0; nt < 2; ++nt) acc1[mt][nt] = (f32x4){0.f,0.f,0.f,0.f};
  #pragma unroll
  for (int kt = 0; kt < 2; ++kt) {
    #pragma unroll
    for (int nt = 0; nt < 2; ++nt) {
      int ncol = wv*32 + nt*16 + (lane & 15);
      h8 bfrag = *(const h8*)(w1h + ncol*64 + kt*32 + (lane >> 4)*8);
      #pragma unroll
      for (int mt = 0; mt < 2; ++mt) {
        h8 afrag = *(const h8*)&sA[(mt*16 + (lane & 15))*72 + kt*32 + (lane >> 4)*8];
        acc1[mt][nt] = __builtin_amdgcn_mfma_f32_16x16x32_f16(afrag, bfrag, acc1[mt][nt], 0, 0, 0);
      }
    }
  }
  // ---- bias + exact GELU -> sH (fp16)
  #pragma unroll
  for (int nt = 0; nt < 2; ++nt) {
    int ncol = wv*32 + nt*16 + (lane & 15);
    float b1v = b1[ncol];
    #pragma unroll
    for (int mt = 0; mt < 2; ++mt) {
      #pragma unroll
      for (int r2 = 0; r2 < 4; ++r2) {
        int mrow = mt*16 + (lane >> 4)*4 + r2;
        float h = acc1[mt][nt][r2] + b1v;
        float g = 0.5f * h * (1.f + erff(h * 0.70710678118f));
        sH[mrow*136 + ncol] = f2h(g);
      }
    }
  }
  __syncthreads();
  // ---- GEMM2: [32x128] x W2^T -> [32x64], n-slice 16 per wave
  f32x4 acc2[2];
  #pragma unroll
  for (int mt = 0; mt < 2; ++mt) acc2[mt] = (f32x4){0.f,0.f,0.f,0.f};
  int ocol = wv*16 + (lane & 15);
  #pragma unroll
  for (int kt = 0; kt < 4; ++kt) {
    h8 bfrag = *(const h8*)(w2h + ocol*128 + kt*32 + (lane >> 4)*8);
    #pragma unroll
    for (int mt = 0; mt < 2; ++mt) {
      h8 afrag = *(const h8*)&sH[(mt*16 + (lane & 15))*136 + kt*32 + (lane >> 4)*8];
      acc2[mt] = __builtin_amdgcn_mfma_f32_16x16x32_f16(afrag, bfrag, acc2[mt], 0, 0, 0);
    }
  }
  // ---- residual + bias + transpose store
  float b2v = b2[ocol];
  int bb = m0 >> 14;
  #pragma unroll
  for (int mt = 0; mt < 2; ++mt) {
    int mrow = mt*16 + (lane >> 4)*4;
    int l = m0 + mrow;
    const float* yp = y2 + (size_t)l * 64 + ocol;
    float4 o4;
    o4.x = yp[0]   + acc2[mt][0] + b2v;
    o4.y = yp[64]  + acc2[mt][1] + b2v;
    o4.z = yp[128] + acc2[mt][2] + b2v;
    o4.w = yp[192] + acc2[mt][3] + b2v;
    *(float4*)&out[(size_t)bb * 64 * LL + (size_t)ocol * LL + (l - (bb << 14))] = o4;
  }
}

extern "C" void kernel_launch(void* const* d_in, const int* in_sizes, int n_in,
                              void* d_out, int out_size, void* d_ws, size_t ws_size,
                              hipStream_t stream) {
  const float* x         = (const float*)d_in[0];
  const float* qkv_w     = (const float*)d_in[1];
  const float* qkv_b     = (const float*)d_in[2];
  const float* rel_table = (const float*)d_in[3];
  const float* n1w       = (const float*)d_in[4];
  const float* n1b       = (const float*)d_in[5];
  const float* n2w       = (const float*)d_in[6];
  const float* n2b       = (const float*)d_in[7];
  const float* proj_w    = (const float*)d_in[8];
  const float* proj_b    = (const float*)d_in[9];
  const float* fw        = (const float*)d_in[10];
  const float* fb        = (const float*)d_in[11];
  const float* w1        = (const float*)d_in[12];
  const float* b1        = (const float*)d_in[13];
  const float* w2        = (const float*)d_in[14];
  const float* b2        = (const float*)d_in[15];

  char* ws = (char*)d_ws;
  unsigned short* q    = (unsigned short*)(ws);                    // BL*32 fp16 = 2MB
  unsigned short* k    = (unsigned short*)(ws + 2097152);          // 2MB
  unsigned short* v    = (unsigned short*)(ws + 4194304);          // 2MB
  float*          y2   = (float*)(ws + 6291456);                   // BL*64 f32 = 8MB
  unsigned short* wctT = (unsigned short*)(ws + 14680064);         // 64*800 fp16
  float*          bc   = (float*)(ws + 14782464);                  // 64 f32
  unsigned short* w1h  = (unsigned short*)(ws + 14782720);         // 8192 fp16
  unsigned short* w2h  = (unsigned short*)(ws + 14799104);         // 8192 fp16
  float* out = (float*)d_out;

  k_combine<<<203, 256, 0, stream>>>(proj_w, proj_b, fw, fb, w1, w2, wctT, bc, w1h, w2h);
  k_ln_qkv<<<dim3(BL/128, 3), 128, 0, stream>>>(x, qkv_w, qkv_b, n1w, n1b, q, k, v);
  k_attn<<<dim3(WW/TW, HH/TH, 2), 256, 0, stream>>>(q, k, v, rel_table, wctT, bc, y2);
  k_mlp<<<BL/32, 256, 0, stream>>>(y2, n2w, n2b, w1h, b1, w2h, b2, out);
}